// Round 8
// baseline (510.765 us; speedup 1.0000x reference)
//
#include <hip/hip_runtime.h>

#define S_LEN 2048
#define NB    2
#define NH    16
#define NKV   4
#define HDIM  256
#define LW    10752   // Ycat row width: 8192 (q|gate) + 1024 (k) + 1024 (v) + 512 (r)

using bf16x8 = __attribute__((ext_vector_type(8))) short;
using s16x4  = __attribute__((ext_vector_type(4))) short;
using f32x4  = __attribute__((ext_vector_type(4))) float;

__device__ __forceinline__ float bf2f(short u){
  union { float f; unsigned u; } x; x.u = ((unsigned)(unsigned short)u) << 16; return x.f;
}
__device__ __forceinline__ short f2bf(float f){
  unsigned i = __builtin_bit_cast(unsigned, f);
  unsigned r = (i + 0x7fffu + ((i >> 16) & 1u)) >> 16;
  return (short)r;
}
__device__ __forceinline__ float sigm(float x){ return 1.0f / (1.0f + __expf(-x)); }

__device__ __forceinline__ void gload16(const short* g, short* lds){
  __builtin_amdgcn_global_load_lds((const __attribute__((address_space(1))) void*)g,
                                   (__attribute__((address_space(3))) void*)lds,
                                   16, 0, 0);
}

// ---------------- f32 -> bf16 elementwise ----------------
__global__ void k_cvt(const float* __restrict__ in, short* __restrict__ out, int n4){
  int i = blockIdx.x * blockDim.x + threadIdx.x;
  if (i >= n4) return;
  float4 v = ((const float4*)in)[i];
  s16x4 o;
  o[0] = f2bf(v.x); o[1] = f2bf(v.y); o[2] = f2bf(v.z); o[3] = f2bf(v.w);
  ((s16x4*)out)[i] = o;
}

// ---------------- split-K reduce: o += b (n4 = float4 count!) ----------------
__global__ void k_add(const float* __restrict__ b, float* __restrict__ o, int n4){
  int i = blockIdx.x * blockDim.x + threadIdx.x;
  const int stride = gridDim.x * blockDim.x;
  for (; i < n4; i += stride) {
    float4 x = ((const float4*)o)[i];
    float4 y = ((const float4*)b)[i];
    float4 z = {x.x + y.x, x.y + y.y, x.z + y.z, x.w + y.w};
    ((float4*)o)[i] = z;
  }
}

// ------- fused weight transpose+convert v2: 64x64 tiles, packed 16B stores -------
__global__ __launch_bounds__(256) void k_wt(const float* __restrict__ Wq,
                     const float* __restrict__ Wk, const float* __restrict__ Wv,
                     const float* __restrict__ Wr, const float* __restrict__ Wo,
                     short* __restrict__ WcatT, short* __restrict__ WoT)
{
  __shared__ float tile[64][65];
  const int id = blockIdx.x;
  const float* src; short* dst; int R, C, Ct, local;
  if (id < 4096)      { src = Wq; dst = WcatT;                      R = 2048; C = 8192; Ct = 128; local = id; }
  else if (id < 4608) { src = Wk; dst = WcatT + (size_t)8192*2048;  R = 2048; C = 1024; Ct =  16; local = id - 4096; }
  else if (id < 5120) { src = Wv; dst = WcatT + (size_t)9216*2048;  R = 2048; C = 1024; Ct =  16; local = id - 4608; }
  else if (id < 5376) { src = Wr; dst = WcatT + (size_t)10240*2048; R = 2048; C =  512; Ct =   8; local = id - 5120; }
  else                { src = Wo; dst = WoT;                        R = 4096; C = 2048; Ct =  32; local = id - 5376; }
  const int c0 = (local % Ct) * 64, r0 = (local / Ct) * 64;
  const int t = threadIdx.x;
  const int rr = t >> 2, cg = (t & 3) * 16;
  #pragma unroll
  for (int j = 0; j < 4; ++j)
    *(float4*)&tile[rr][cg + j*4] = *(const float4*)&src[(size_t)(r0 + rr) * C + c0 + cg + j*4];
  __syncthreads();
  unsigned u[8];
  #pragma unroll
  for (int j = 0; j < 8; ++j) {
    float lo = tile[cg + 2*j][rr], hi = tile[cg + 2*j + 1][rr];
    asm("v_cvt_pk_bf16_f32 %0, %1, %2" : "=v"(u[j]) : "v"(lo), "v"(hi));
  }
  uint4 u0 = {u[0], u[1], u[2], u[3]}, u1 = {u[4], u[5], u[6], u[7]};
  short* dp = &dst[(size_t)(c0 + rr) * R + r0 + cg];
  *(uint4*)dp = u0;
  *(uint4*)(dp + 8) = u1;
}

// ---------------- bf16 V-slice transpose: Ycat v -> VT[b,hk,d,s] ----------------
__global__ void k_vt(const short* __restrict__ Ycat, short* __restrict__ VT){
  __shared__ short tile[32][33];
  int b = blockIdx.z >> 2, hk = blockIdx.z & 3;
  int s0 = blockIdx.x * 32, d0 = blockIdx.y * 32;
  int tx = threadIdx.x, ty = threadIdx.y;   // (32, 8)
  #pragma unroll
  for (int i = ty; i < 32; i += 8)
    tile[i][tx] = Ycat[(size_t)(b * S_LEN + s0 + i) * LW + 9216 + hk * 256 + d0 + tx];
  __syncthreads();
  #pragma unroll
  for (int i = ty; i < 32; i += 8)
    VT[(size_t)((b * NKV + hk) * HDIM + d0 + i) * S_LEN + s0 + tx] = tile[tx][i];
}

// ================= 256x256 8-phase bf16 GEMM (T1+T2+T3/T4+T5) =================
#define MFMA_(a, b, c) __builtin_amdgcn_mfma_f32_16x16x32_bf16(a, b, c, 0, 0, 0)
#define As ((short(*)[2][8192])(SMEM))
#define Bs ((short(*)[2][8192])(SMEM + 32768))
#define LDA_(buf, ks, mh, f) (*(const bf16x8*)&As[buf][ks][(wm*128 + (mh)*64 + (f)*16 + l15) * 32 + rdSlot])
#define LDB_(buf, ks, f)     (*(const bf16x8*)&Bs[buf][ks][(wn*64  + (f)*16 + l15) * 32 + rdSlot])
#define STAGE_A_(buf, ks, tile) { \
  gload16(aG0 + (size_t)(tile)*64 + (ks)*32, &As[buf][ks][w*512]); \
  gload16(aG1 + (size_t)(tile)*64 + (ks)*32, &As[buf][ks][4096 + w*512]); }
#define STAGE_B_(buf, ks, tile) { \
  gload16(bG0 + (size_t)(tile)*64 + (ks)*32, &Bs[buf][ks][w*512]); \
  gload16(bG1 + (size_t)(tile)*64 + (ks)*32, &Bs[buf][ks][4096 + w*512]); }
#define VM4 asm volatile("s_waitcnt vmcnt(4)" ::: "memory");
#define PH_(buf, ks, mh, LB, ...) { \
  bf16x8 a0 = LDA_(buf,ks,mh,0), a1 = LDA_(buf,ks,mh,1), a2 = LDA_(buf,ks,mh,2), a3 = LDA_(buf,ks,mh,3); \
  if (LB) { b0 = LDB_(buf,ks,0); b1 = LDB_(buf,ks,1); b2 = LDB_(buf,ks,2); b3 = LDB_(buf,ks,3); } \
  __VA_ARGS__ \
  __builtin_amdgcn_s_barrier(); \
  asm volatile("s_waitcnt lgkmcnt(0)" ::: "memory"); \
  __builtin_amdgcn_s_setprio(1); \
  acc[(mh)*4+0][0] = MFMA_(a0, b0, acc[(mh)*4+0][0]); \
  acc[(mh)*4+0][1] = MFMA_(a0, b1, acc[(mh)*4+0][1]); \
  acc[(mh)*4+0][2] = MFMA_(a0, b2, acc[(mh)*4+0][2]); \
  acc[(mh)*4+0][3] = MFMA_(a0, b3, acc[(mh)*4+0][3]); \
  acc[(mh)*4+1][0] = MFMA_(a1, b0, acc[(mh)*4+1][0]); \
  acc[(mh)*4+1][1] = MFMA_(a1, b1, acc[(mh)*4+1][1]); \
  acc[(mh)*4+1][2] = MFMA_(a1, b2, acc[(mh)*4+1][2]); \
  acc[(mh)*4+1][3] = MFMA_(a1, b3, acc[(mh)*4+1][3]); \
  acc[(mh)*4+2][0] = MFMA_(a2, b0, acc[(mh)*4+2][0]); \
  acc[(mh)*4+2][1] = MFMA_(a2, b1, acc[(mh)*4+2][1]); \
  acc[(mh)*4+2][2] = MFMA_(a2, b2, acc[(mh)*4+2][2]); \
  acc[(mh)*4+2][3] = MFMA_(a2, b3, acc[(mh)*4+2][3]); \
  acc[(mh)*4+3][0] = MFMA_(a3, b0, acc[(mh)*4+3][0]); \
  acc[(mh)*4+3][1] = MFMA_(a3, b1, acc[(mh)*4+3][1]); \
  acc[(mh)*4+3][2] = MFMA_(a3, b2, acc[(mh)*4+3][2]); \
  acc[(mh)*4+3][3] = MFMA_(a3, b3, acc[(mh)*4+3][3]); \
  __builtin_amdgcn_s_setprio(0); \
  __builtin_amdgcn_s_barrier(); }

template<int OUTF32, int CM, int SPLITK>
__global__ __launch_bounds__(512) void k_gemm2(const short* __restrict__ A,
                                               const short* __restrict__ BT,
                                               void* __restrict__ C0,
                                               void* __restrict__ C1,
                                               int M, int N, int Kpitch, int Klen,
                                               int gx)
{
  __shared__ __align__(16) short SMEM[65536];   // As | Bs ; epilogue: fp32 stage
  const int t = threadIdx.x, lane = t & 63, w = t >> 6;
  const int l15 = lane & 15;
  const int wm = w >> 2, wn = w & 3;
  const int rdSlot = (((lane >> 4) ^ ((lane >> 1) & 3)) * 8);

  const int nwg = gridDim.x;
  const int swz = (blockIdx.x & 7) * (nwg >> 3) + (blockIdx.x >> 3);
  int rem = swz, kOff = 0;
  void* Cp = C0;
  if (SPLITK) {                 // nwg == 256: top bit selects K-half
    rem = swz & 127;
    if (swz >> 7) { kOff = Klen; Cp = C1; }
  }
  const int m0 = (CM ? (rem % gx) : (rem / gx)) * 256;
  const int n0 = (CM ? (rem / gx) : (rem % gx)) * 256;

  const int sRow = w * 16 + (lane >> 2);
  const int sSwz = ((lane & 3) ^ ((lane >> 3) & 3)) * 8;
  const short* aG0 = A  + (size_t)(m0 + sRow) * Kpitch + kOff + sSwz;
  const short* aG1 = A  + (size_t)(m0 + 128 + sRow) * Kpitch + kOff + sSwz;
  const short* bG0 = BT + (size_t)(n0 + sRow) * Kpitch + kOff + sSwz;
  const short* bG1 = BT + (size_t)(n0 + 128 + sRow) * Kpitch + kOff + sSwz;

  f32x4 acc[8][4] = {};
  bf16x8 b0 = {}, b1 = {}, b2 = {}, b3 = {};

  STAGE_A_(0, 0, 0) STAGE_A_(0, 1, 0) STAGE_B_(0, 0, 0) STAGE_B_(0, 1, 0)
  STAGE_A_(1, 0, 1) STAGE_B_(1, 0, 1)
  asm volatile("s_waitcnt vmcnt(4)" ::: "memory");
  __builtin_amdgcn_s_barrier();

  const int nIt = Klen >> 7;
  for (int i = 0; i < nIt; ++i) {
    const int c = 2 * i;
    const bool st = (i + 1 < nIt);
    PH_(0, 0, 0, 1, STAGE_A_(1, 1, c + 1))
    PH_(0, 0, 1, 0, STAGE_B_(1, 1, c + 1))
    PH_(0, 1, 0, 1, if (st) STAGE_A_(0, 0, c + 2))
    PH_(0, 1, 1, 0, if (st) STAGE_B_(0, 0, c + 2) VM4)
    PH_(1, 0, 0, 1, if (st) STAGE_A_(0, 1, c + 2))
    PH_(1, 0, 1, 0, if (st) STAGE_B_(0, 1, c + 2))
    PH_(1, 1, 0, 1, if (st) STAGE_A_(1, 0, c + 3))
    PH_(1, 1, 1, 0, if (st) STAGE_B_(1, 0, c + 3) VM4)
  }

  // ---- epilogue: LDS transpose (4 chunks of 64 rows x 256 cols, pitch 260) ----
  float* Cl = (float*)SMEM;
  const int g = lane >> 4;
  #pragma unroll
  for (int ch = 0; ch < 4; ++ch) {
    if (wm == (ch >> 1)) {
      #pragma unroll
      for (int ii2 = 0; ii2 < 4; ++ii2)
        #pragma unroll
        for (int j = 0; j < 4; ++j)
          #pragma unroll
          for (int r = 0; r < 4; ++r)
            Cl[(ii2*16 + g*4 + r) * 260 + wn*64 + j*16 + l15] = acc[(ch & 1)*4 + ii2][j][r];
    }
    asm volatile("s_waitcnt lgkmcnt(0)" ::: "memory");
    __builtin_amdgcn_s_barrier();
    #pragma unroll
    for (int p = 0; p < 4; ++p) {
      const int row = (t >> 5) + p * 16;
      const int c8 = (t & 31) * 8;
      f32x4 v0 = *(const f32x4*)&Cl[row * 260 + c8];
      f32x4 v1 = *(const f32x4*)&Cl[row * 260 + c8 + 4];
      const int grow = m0 + ch * 64 + row;
      if (OUTF32) {
        *(f32x4*)&((float*)Cp)[(size_t)grow * N + n0 + c8]     = v0;
        *(f32x4*)&((float*)Cp)[(size_t)grow * N + n0 + c8 + 4] = v1;
      } else {
        unsigned d0, d1, d2, d3;
        asm("v_cvt_pk_bf16_f32 %0, %1, %2" : "=v"(d0) : "v"(v0[0]), "v"(v0[1]));
        asm("v_cvt_pk_bf16_f32 %0, %1, %2" : "=v"(d1) : "v"(v0[2]), "v"(v0[3]));
        asm("v_cvt_pk_bf16_f32 %0, %1, %2" : "=v"(d2) : "v"(v1[0]), "v"(v1[1]));
        asm("v_cvt_pk_bf16_f32 %0, %1, %2" : "=v"(d3) : "v"(v1[2]), "v"(v1[3]));
        uint4 u = {d0, d1, d2, d3};
        *(uint4*)&((short*)Cp)[(size_t)grow * N + n0 + c8] = u;
      }
    }
    asm volatile("s_waitcnt lgkmcnt(0)" ::: "memory");
    __builtin_amdgcn_s_barrier();
  }
}
#undef As
#undef Bs

// ---------------- per-token: RMSNorm(q,k), gates, partial RoPE, in place ----------------
__global__ __launch_bounds__(256) void k_post(short* __restrict__ Ycat,
    const float* __restrict__ cosb, const float* __restrict__ sinb,
    const float* __restrict__ qw, const float* __restrict__ kw)
{
  const int tok = blockIdx.x;                 // b*S + s
  const int lane = threadIdx.x & 63, w = threadIdx.x >> 6;
  const size_t rowb = (size_t)tok * LW;
  const int d0 = lane * 4;

  float gq[4], gv[4];
  {
    s16x4 a  = *(const s16x4*)&Ycat[rowb + 10240 + d0];
    s16x4 bq = *(const s16x4*)&Ycat[rowb + 10240 + 256 + d0];
    #pragma unroll
    for (int j = 0; j < 4; ++j){ gq[j] = sigm(bf2f(a[j])); gv[j] = sigm(bf2f(bq[j])); }
  }
  float c4[4] = {0,0,0,0}, s4[4] = {0,0,0,0};
  if (lane < 16) {
    float4 c = *(const float4*)&cosb[(size_t)tok * 64 + d0];
    float4 s = *(const float4*)&sinb[(size_t)tok * 64 + d0];
    c4[0]=c.x; c4[1]=c.y; c4[2]=c.z; c4[3]=c.w;
    s4[0]=s.x; s4[1]=s.y; s4[2]=s.z; s4[3]=s.w;
  }
  float4 qv4 = *(const float4*)&qw[d0];
  float4 kv4 = *(const float4*)&kw[d0];
  float qwa[4] = {qv4.x, qv4.y, qv4.z, qv4.w};
  float kwa[4] = {kv4.x, kv4.y, kv4.z, kv4.w};

  #pragma unroll
  for (int hi = 0; hi < 4; ++hi) {
    const int hh = w * 4 + hi;
    const size_t off = rowb + hh * 512 + d0;
    s16x4 v = *(const s16x4*)&Ycat[off];
    float x[4];
    #pragma unroll
    for (int j = 0; j < 4; ++j) x[j] = bf2f(v[j]);
    float ss = x[0]*x[0] + x[1]*x[1] + x[2]*x[2] + x[3]*x[3];
    #pragma unroll
    for (int o2 = 1; o2 < 64; o2 <<= 1) ss += __shfl_xor(ss, o2);
    float rr = rsqrtf(ss * (1.0f/256.0f) + 1e-6f);
    #pragma unroll
    for (int j = 0; j < 4; ++j) x[j] = x[j] * rr * (1.0f + qwa[j]) * gq[j];
    float p[4];
    #pragma unroll
    for (int j = 0; j < 4; ++j) p[j] = __shfl_xor(x[j], 8);
    if (lane < 8)       { for (int j = 0; j < 4; ++j) x[j] = x[j]*c4[j] - p[j]*s4[j]; }
    else if (lane < 16) { for (int j = 0; j < 4; ++j) x[j] = x[j]*c4[j] + p[j]*s4[j]; }
    s16x4 o;
    #pragma unroll
    for (int j = 0; j < 4; ++j) o[j] = f2bf(x[j]);
    *(s16x4*)&Ycat[off] = o;
  }
  {
    const size_t off = rowb + 8192 + w * 256 + d0;
    s16x4 v = *(const s16x4*)&Ycat[off];
    float x[4];
    #pragma unroll
    for (int j = 0; j < 4; ++j) x[j] = bf2f(v[j]);
    float ss = x[0]*x[0] + x[1]*x[1] + x[2]*x[2] + x[3]*x[3];
    #pragma unroll
    for (int o2 = 1; o2 < 64; o2 <<= 1) ss += __shfl_xor(ss, o2);
    float rr = rsqrtf(ss * (1.0f/256.0f) + 1e-6f);
    #pragma unroll
    for (int j = 0; j < 4; ++j) x[j] = x[j] * rr * (1.0f + kwa[j]) * gq[j];
    float p[4];
    #pragma unroll
    for (int j = 0; j < 4; ++j) p[j] = __shfl_xor(x[j], 8);
    if (lane < 8)       { for (int j = 0; j < 4; ++j) x[j] = x[j]*c4[j] - p[j]*s4[j]; }
    else if (lane < 16) { for (int j = 0; j < 4; ++j) x[j] = x[j]*c4[j] + p[j]*s4[j]; }
    s16x4 o;
    #pragma unroll
    for (int j = 0; j < 4; ++j) o[j] = f2bf(x[j]);
    *(s16x4*)&Ycat[off] = o;
  }
  {
    const size_t off = rowb + 9216 + w * 256 + d0;
    s16x4 v = *(const s16x4*)&Ycat[off];
    s16x4 o;
    #pragma unroll
    for (int j = 0; j < 4; ++j) o[j] = f2bf(bf2f(v[j]) * gv[j]);
    *(s16x4*)&Ycat[off] = o;
  }
}

// ====== flash attention v4: 32 q-rows/wave (two fragment sets share K/V reads) ======
// grid 512: id = widx*8 + xcd; xcd=(b,hk); widx = (qsel-coset x)*4 + head.
// Block covers 128 q-rows; wave w owns rows q0+w*32 .. +31 (sets A: +l15, B: +16+l15).
#define ATT_STAGE(bb, jj) { \
  _Pragma("unroll") \
  for (int ri = 0; ri < 4; ++ri) \
    gload16(kSrc + (size_t)((jj) + ri*8) * LW, &Ks[bb][t*8 + ri*2048]); \
  _Pragma("unroll") \
  for (int ri = 0; ri < 4; ++ri) \
    gload16(vSrc + (jj) + (size_t)(ri*64) * S_LEN, &Vs[bb][t*8 + ri*2048]); }

#define SOFTMAX_SET(sa, qgX, m_r, l_r, oacc, Pww, paX) { \
  float s[8]; \
  _Pragma("unroll") \
  for (int c = 0; c < 2; ++c) \
    _Pragma("unroll") \
    for (int r = 0; r < 4; ++r) s[c*4+r] = sa[c][r]; \
  if (j0 + 31 > (qgX)) { \
    _Pragma("unroll") \
    for (int c = 0; c < 2; ++c) \
      _Pragma("unroll") \
      for (int r = 0; r < 4; ++r) \
        if (j0 + c*16 + g*4 + r > (qgX)) s[c*4+r] = -1e30f; \
  } \
  float mx = s[0]; \
  _Pragma("unroll") \
  for (int i2 = 1; i2 < 8; ++i2) mx = fmaxf(mx, s[i2]); \
  mx = fmaxf(mx, __shfl_xor(mx, 16)); \
  mx = fmaxf(mx, __shfl_xor(mx, 32)); \
  if (!__all(mx - m_r <= 128.0f)) { \
    const float mnew = fmaxf(m_r, mx); \
    const float alpha = exp2f((m_r - mnew) * SC2); \
    l_r *= alpha; \
    _Pragma("unroll") \
    for (int jb = 0; jb < 16; ++jb) \
      _Pragma("unroll") \
      for (int r = 0; r < 4; ++r) oacc[jb][r] *= alpha; \
    m_r = mnew; \
  } \
  float p[8], rs = 0.0f; \
  _Pragma("unroll") \
  for (int i2 = 0; i2 < 8; ++i2) { p[i2] = exp2f((s[i2] - m_r) * SC2); rs += p[i2]; } \
  rs += __shfl_xor(rs, 16); \
  rs += __shfl_xor(rs, 32); \
  l_r += rs; \
  _Pragma("unroll") \
  for (int c = 0; c < 2; ++c) { \
    uint2 u; \
    u.x = (unsigned short)f2bf(p[c*4+0]) | ((unsigned)(unsigned short)f2bf(p[c*4+1]) << 16); \
    u.y = (unsigned short)f2bf(p[c*4+2]) | ((unsigned)(unsigned short)f2bf(p[c*4+3]) << 16); \
    *(uint2*)((Pww) + ((c * 32 + 8 * g) ^ pswz)) = u; \
  } \
  paX = *(const bf16x8*)((Pww) + ((16 * g) ^ pswz)); }

__global__ __launch_bounds__(256, 2) void k_attn(const short* __restrict__ Ycat,
                                                 const short* __restrict__ VT,
                                                 short* __restrict__ AO)
{
  __shared__ __align__(16) short Ks[2][8192];   // [buf][32 rows x 256]
  __shared__ __align__(16) short Vs[2][8192];   // [buf][256 rows x 32]
  __shared__ __align__(16) short Ps[4][1024];   // per-wave [2 sets][16 x 32]

  const int t = threadIdx.x, lane = t & 63, w = t >> 6;
  const int l15 = lane & 15, g = lane >> 4;
  const int id = blockIdx.x;
  const int xcd = id & 7, widx = id >> 3;
  const int b = xcd >> 2, hk = xcd & 3;
  const int h = hk * 4 + (widx & 3);
  const int x = widx >> 2;                       // 0..15
  const int qsel = (x < 8) ? 15 - x : x - 8;     // pair (x, x+8) sums 15 (LPT)
  const int q0 = qsel * 128;
  const int qgA = q0 + w * 32 + l15;
  const int qgB = qgA + 16;
  const float SC2 = 0.09016844f;                 // 1/16 * log2(e)

  bf16x8 qfA[8], qfB[8];
  {
    const size_t qa = ((size_t)(b * S_LEN) + qgA) * LW + h * 512 + g * 8;
    const size_t qb = ((size_t)(b * S_LEN) + qgB) * LW + h * 512 + g * 8;
    #pragma unroll
    for (int kk = 0; kk < 8; ++kk) {
      qfA[kk] = *(const bf16x8*)&Ycat[qa + kk * 32];
      qfB[kk] = *(const bf16x8*)&Ycat[qb + kk * 32];
    }
  }
  asm volatile("s_waitcnt vmcnt(0)" ::: "memory");

  const int kRow = t >> 5;
  const int kColS = ((((t & 31) * 16) ^ ((kRow & 7) << 4)) >> 1);
  const int vRow = t >> 2;
  const int vColS = ((((t & 3) * 16) ^ ((vRow & 3) << 4)) >> 1);
  const short* kSrc = Ycat + ((size_t)(b * S_LEN) + kRow) * LW + 8192 + hk * 256 + kColS;
  const short* vSrc = VT + ((size_t)((b * NKV + hk) * HDIM + vRow)) * S_LEN + vColS;

  f32x4 oaccA[16] = {}, oaccB[16] = {};
  float m_rA = -1e30f, l_rA = 0.0f, m_rB = -1e30f, l_rB = 0.0f;

  const int nt = (q0 >> 5) + 4;
  ATT_STAGE(0, 0)
  int buf = 0;
  char* PwA = (char*)Ps[w] + l15 * 64;
  char* PwB = PwA + 1024;
  const int pswz = (l15 & 3) << 4;

  for (int ti = 0; ti < nt; ++ti) {
    const int j0 = ti * 32;
    const int jn = (ti + 1 < nt) ? j0 + 32 : 0;   // dummy re-stage keeps vmcnt uniform
    ATT_STAGE(buf ^ 1, jn)
    asm volatile("s_waitcnt vmcnt(8)" ::: "memory");
    __builtin_amdgcn_s_barrier();

    if (j0 <= q0 + w * 32 + 31) {                 // wave-uniform causal skip
      f32x4 saA[2] = {}, saB[2] = {};
      #pragma unroll
      for (int kk = 0; kk < 8; ++kk) {
        #pragma unroll
        for (int c = 0; c < 2; ++c) {
          const int row = c * 16 + l15;
          bf16x8 kf = *(const bf16x8*)((const char*)Ks[buf] + row * 512
                       + ((kk * 64 + g * 16) ^ ((l15 & 7) << 4)));
          saA[c] = __builtin_amdgcn_mfma_f32_16x16x32_bf16(kf, qfA[kk], saA[c], 0, 0, 0);
          saB[c] = __builtin_amdgcn_mfma_f32_16x16x32_bf16(kf, qfB[kk], saB[c], 0, 0, 0);
        }
      }
      bf16x8 paA, paB;
      SOFTMAX_SET(saA, qgA, m_rA, l_rA, oaccA, PwA, paA)
      SOFTMAX_SET(saB, qgB, m_rB, l_rB, oaccB, PwB, paB)
      #pragma unroll
      for (int jb = 0; jb < 16; ++jb) {
        const int vrow = jb * 16 + l15;
        bf16x8 vf = *(const bf16x8*)((const char*)Vs[buf] + vrow * 64
                     + ((16 * g) ^ ((l15 & 3) << 4)));
        oaccA[jb] = __builtin_amdgcn_mfma_f32_16x16x32_bf16(vf, paA, oaccA[jb], 0, 0, 0);
        oaccB[jb] = __builtin_amdgcn_mfma_f32_16x16x32_bf16(vf, paB, oaccB[jb], 0, 0, 0);
      }
    }
    __builtin_amdgcn_s_barrier();
    buf ^= 1;
  }
  asm volatile("s_waitcnt vmcnt(0)" ::: "memory");  // drain dummy stage

  const float linvA = 1.0f / l_rA, linvB = 1.0f / l_rB;
  const size_t gbA = ((size_t)(b * S_LEN) + qgA) * LW + h * 512 + 256;
  const size_t obA = ((size_t)(b * S_LEN) + qgA) * 4096 + h * 256;
  const size_t gbB = ((size_t)(b * S_LEN) + qgB) * LW + h * 512 + 256;
  const size_t obB = ((size_t)(b * S_LEN) + qgB) * 4096 + h * 256;
  #pragma unroll
  for (int jb = 0; jb < 16; ++jb) {
    const int d0 = jb * 16 + g * 4;
    s16x4 gtA = *(const s16x4*)&Ycat[gbA + d0];
    s16x4 gtB = *(const s16x4*)&Ycat[gbB + d0];
    s16x4 oA, oB;
    #pragma unroll
    for (int r = 0; r < 4; ++r) {
      oA[r] = f2bf(oaccA[jb][r] * linvA * sigm(bf2f(gtA[r])));
      oB[r] = f2bf(oaccB[jb][r] * linvB * sigm(bf2f(gtB[r])));
    }
    *(s16x4*)&AO[obA + d0] = oA;
    *(s16x4*)&AO[obB + d0] = oB;
  }
}

extern "C" void kernel_launch(void* const* d_in, const int* in_sizes, int n_in,
                              void* d_out, int out_size, void* d_ws, size_t ws_size,
                              hipStream_t stream) {
  const float* X    = (const float*)d_in[0];
  const float* cosb = (const float*)d_in[1];
  const float* sinb = (const float*)d_in[2];
  const float* Wq   = (const float*)d_in[4];
  const float* Wk   = (const float*)d_in[5];
  const float* Wv   = (const float*)d_in[6];
  const float* Wo   = (const float*)d_in[7];
  const float* qw   = (const float*)d_in[8];
  const float* kw   = (const float*)d_in[9];
  const float* Wr   = (const float*)d_in[10];

  short* Xb    = (short*)d_ws;                       //  8,388,608
  short* WcatT = Xb    +  8388608;                   // 22,020,096
  short* AO    = WcatT;                              // alias (dead after GEMM0)
  short* WoT   = WcatT + 22020096;                   //  8,388,608
  short* Ycat  = WoT   +  8388608;                   // 44,040,192
  short* VT    = Ycat  + 44040192;                   //  4,194,304
  float* P1    = (float*)Ycat;                       // split-K partial (Ycat dead then)

  dim3 tb(32, 8);
  k_cvt<<<8192, 256, 0, stream>>>(X, Xb, 2097152);
  k_wt<<<7424, 256, 0, stream>>>(Wq, Wk, Wv, Wr, Wo, WcatT, WoT);

  k_gemm2<0, 1, 0><<<672, 512, 0, stream>>>(Xb, WcatT, Ycat, nullptr,
                                            4096, 10752, 2048, 2048, 16);
  k_post<<<4096, 256, 0, stream>>>(Ycat, cosb, sinb, qw, kw);
  k_vt<<<dim3(64, 8, 8), tb, 0, stream>>>(Ycat, VT);
  k_attn<<<512, 256, 0, stream>>>(Ycat, VT, AO);
  k_gemm2<1, 0, 1><<<256, 512, 0, stream>>>(AO, WoT, d_out, P1,
                                            4096, 2048, 4096, 2048, 8);
  // d_out has 4096*2048 = 8,388,608 floats = 2,097,152 float4s
  k_add<<<2048, 256, 0, stream>>>(P1, (float*)d_out, 2097152);
}

// Round 10
// 478.823 us; speedup vs baseline: 1.0667x; 1.0667x over previous
//
#include <hip/hip_runtime.h>

#define S_LEN 2048
#define NB    2
#define NH    16
#define NKV   4
#define HDIM  256
#define LW    10752   // Ycat row width: 8192 (q|gate) + 1024 (k) + 1024 (v) + 512 (r)

using bf16x8 = __attribute__((ext_vector_type(8))) short;
using s16x4  = __attribute__((ext_vector_type(4))) short;
using f32x4  = __attribute__((ext_vector_type(4))) float;

__device__ __forceinline__ float bf2f(short u){
  union { float f; unsigned u; } x; x.u = ((unsigned)(unsigned short)u) << 16; return x.f;
}
__device__ __forceinline__ short f2bf(float f){
  unsigned i = __builtin_bit_cast(unsigned, f);
  unsigned r = (i + 0x7fffu + ((i >> 16) & 1u)) >> 16;
  return (short)r;
}
__device__ __forceinline__ float sigm(float x){ return 1.0f / (1.0f + __expf(-x)); }

__device__ __forceinline__ void gload16(const short* g, short* lds){
  __builtin_amdgcn_global_load_lds((const __attribute__((address_space(1))) void*)g,
                                   (__attribute__((address_space(3))) void*)lds,
                                   16, 0, 0);
}

// ---------------- f32 -> bf16 elementwise ----------------
__global__ void k_cvt(const float* __restrict__ in, short* __restrict__ out, int n4){
  int i = blockIdx.x * blockDim.x + threadIdx.x;
  if (i >= n4) return;
  float4 v = ((const float4*)in)[i];
  s16x4 o;
  o[0] = f2bf(v.x); o[1] = f2bf(v.y); o[2] = f2bf(v.z); o[3] = f2bf(v.w);
  ((s16x4*)out)[i] = o;
}

// ---------------- split-K reduce: o += b (n4 = float4 count!) ----------------
__global__ void k_add(const float* __restrict__ b, float* __restrict__ o, int n4){
  int i = blockIdx.x * blockDim.x + threadIdx.x;
  const int stride = gridDim.x * blockDim.x;
  for (; i < n4; i += stride) {
    float4 x = ((const float4*)o)[i];
    float4 y = ((const float4*)b)[i];
    float4 z = {x.x + y.x, x.y + y.y, x.z + y.z, x.w + y.w};
    ((float4*)o)[i] = z;
  }
}

// ------- fused weight transpose+convert v2: 64x64 tiles, packed 16B stores -------
// Tile counts: Wq 4096 | Wk 512 | Wv 512 | Wr 256 | Wo 2048  => grid 7424 (R8 bug: 5888)
__global__ __launch_bounds__(256) void k_wt(const float* __restrict__ Wq,
                     const float* __restrict__ Wk, const float* __restrict__ Wv,
                     const float* __restrict__ Wr, const float* __restrict__ Wo,
                     short* __restrict__ WcatT, short* __restrict__ WoT)
{
  __shared__ float tile[64][65];
  const int id = blockIdx.x;
  const float* src; short* dst; int R, C, Ct, local;
  if (id < 4096)      { src = Wq; dst = WcatT;                      R = 2048; C = 8192; Ct = 128; local = id; }
  else if (id < 4608) { src = Wk; dst = WcatT + (size_t)8192*2048;  R = 2048; C = 1024; Ct =  16; local = id - 4096; }
  else if (id < 5120) { src = Wv; dst = WcatT + (size_t)9216*2048;  R = 2048; C = 1024; Ct =  16; local = id - 4608; }
  else if (id < 5376) { src = Wr; dst = WcatT + (size_t)10240*2048; R = 2048; C =  512; Ct =   8; local = id - 5120; }
  else                { src = Wo; dst = WoT;                        R = 4096; C = 2048; Ct =  32; local = id - 5376; }
  const int c0 = (local % Ct) * 64, r0 = (local / Ct) * 64;
  const int t = threadIdx.x;
  const int rr = t >> 2, cg = (t & 3) * 16;
  #pragma unroll
  for (int j = 0; j < 4; ++j)
    *(float4*)&tile[rr][cg + j*4] = *(const float4*)&src[(size_t)(r0 + rr) * C + c0 + cg + j*4];
  __syncthreads();
  unsigned u[8];
  #pragma unroll
  for (int j = 0; j < 8; ++j) {
    float lo = tile[cg + 2*j][rr], hi = tile[cg + 2*j + 1][rr];
    asm("v_cvt_pk_bf16_f32 %0, %1, %2" : "=v"(u[j]) : "v"(lo), "v"(hi));
  }
  uint4 u0 = {u[0], u[1], u[2], u[3]}, u1 = {u[4], u[5], u[6], u[7]};
  short* dp = &dst[(size_t)(c0 + rr) * R + r0 + cg];
  *(uint4*)dp = u0;
  *(uint4*)(dp + 8) = u1;
}

// ---------------- bf16 V-slice transpose: Ycat v -> VT[b,hk,d,s] ----------------
__global__ void k_vt(const short* __restrict__ Ycat, short* __restrict__ VT){
  __shared__ short tile[32][33];
  int b = blockIdx.z >> 2, hk = blockIdx.z & 3;
  int s0 = blockIdx.x * 32, d0 = blockIdx.y * 32;
  int tx = threadIdx.x, ty = threadIdx.y;   // (32, 8)
  #pragma unroll
  for (int i = ty; i < 32; i += 8)
    tile[i][tx] = Ycat[(size_t)(b * S_LEN + s0 + i) * LW + 9216 + hk * 256 + d0 + tx];
  __syncthreads();
  #pragma unroll
  for (int i = ty; i < 32; i += 8)
    VT[(size_t)((b * NKV + hk) * HDIM + d0 + i) * S_LEN + s0 + tx] = tile[tx][i];
}

// ================= 256x256 8-phase bf16 GEMM (T1+T2+T3/T4+T5) =================
#define MFMA_(a, b, c) __builtin_amdgcn_mfma_f32_16x16x32_bf16(a, b, c, 0, 0, 0)
#define As ((short(*)[2][8192])(SMEM))
#define Bs ((short(*)[2][8192])(SMEM + 32768))
#define LDA_(buf, ks, mh, f) (*(const bf16x8*)&As[buf][ks][(wm*128 + (mh)*64 + (f)*16 + l15) * 32 + rdSlot])
#define LDB_(buf, ks, f)     (*(const bf16x8*)&Bs[buf][ks][(wn*64  + (f)*16 + l15) * 32 + rdSlot])
#define STAGE_A_(buf, ks, tile) { \
  gload16(aG0 + (size_t)(tile)*64 + (ks)*32, &As[buf][ks][w*512]); \
  gload16(aG1 + (size_t)(tile)*64 + (ks)*32, &As[buf][ks][4096 + w*512]); }
#define STAGE_B_(buf, ks, tile) { \
  gload16(bG0 + (size_t)(tile)*64 + (ks)*32, &Bs[buf][ks][w*512]); \
  gload16(bG1 + (size_t)(tile)*64 + (ks)*32, &Bs[buf][ks][4096 + w*512]); }
#define VM4 asm volatile("s_waitcnt vmcnt(4)" ::: "memory");
#define PH_(buf, ks, mh, LB, ...) { \
  bf16x8 a0 = LDA_(buf,ks,mh,0), a1 = LDA_(buf,ks,mh,1), a2 = LDA_(buf,ks,mh,2), a3 = LDA_(buf,ks,mh,3); \
  if (LB) { b0 = LDB_(buf,ks,0); b1 = LDB_(buf,ks,1); b2 = LDB_(buf,ks,2); b3 = LDB_(buf,ks,3); } \
  __VA_ARGS__ \
  __builtin_amdgcn_s_barrier(); \
  asm volatile("s_waitcnt lgkmcnt(0)" ::: "memory"); \
  __builtin_amdgcn_s_setprio(1); \
  acc[(mh)*4+0][0] = MFMA_(a0, b0, acc[(mh)*4+0][0]); \
  acc[(mh)*4+0][1] = MFMA_(a0, b1, acc[(mh)*4+0][1]); \
  acc[(mh)*4+0][2] = MFMA_(a0, b2, acc[(mh)*4+0][2]); \
  acc[(mh)*4+0][3] = MFMA_(a0, b3, acc[(mh)*4+0][3]); \
  acc[(mh)*4+1][0] = MFMA_(a1, b0, acc[(mh)*4+1][0]); \
  acc[(mh)*4+1][1] = MFMA_(a1, b1, acc[(mh)*4+1][1]); \
  acc[(mh)*4+1][2] = MFMA_(a1, b2, acc[(mh)*4+1][2]); \
  acc[(mh)*4+1][3] = MFMA_(a1, b3, acc[(mh)*4+1][3]); \
  acc[(mh)*4+2][0] = MFMA_(a2, b0, acc[(mh)*4+2][0]); \
  acc[(mh)*4+2][1] = MFMA_(a2, b1, acc[(mh)*4+2][1]); \
  acc[(mh)*4+2][2] = MFMA_(a2, b2, acc[(mh)*4+2][2]); \
  acc[(mh)*4+2][3] = MFMA_(a2, b3, acc[(mh)*4+2][3]); \
  acc[(mh)*4+3][0] = MFMA_(a3, b0, acc[(mh)*4+3][0]); \
  acc[(mh)*4+3][1] = MFMA_(a3, b1, acc[(mh)*4+3][1]); \
  acc[(mh)*4+3][2] = MFMA_(a3, b2, acc[(mh)*4+3][2]); \
  acc[(mh)*4+3][3] = MFMA_(a3, b3, acc[(mh)*4+3][3]); \
  __builtin_amdgcn_s_setprio(0); \
  __builtin_amdgcn_s_barrier(); }

template<int OUTF32, int CM, int SPLITK>
__global__ __launch_bounds__(512) void k_gemm2(const short* __restrict__ A,
                                               const short* __restrict__ BT,
                                               void* __restrict__ C0,
                                               void* __restrict__ C1,
                                               int M, int N, int Kpitch, int Klen,
                                               int gx)
{
  __shared__ __align__(16) short SMEM[65536];   // As | Bs ; epilogue: fp32 stage
  const int t = threadIdx.x, lane = t & 63, w = t >> 6;
  const int l15 = lane & 15;
  const int wm = w >> 2, wn = w & 3;
  const int rdSlot = (((lane >> 4) ^ ((lane >> 1) & 3)) * 8);

  const int nwg = gridDim.x;
  const int swz = (blockIdx.x & 7) * (nwg >> 3) + (blockIdx.x >> 3);
  int rem = swz, kOff = 0;
  void* Cp = C0;
  if (SPLITK) {                 // nwg == 256: top bit selects K-half
    rem = swz & 127;
    if (swz >> 7) { kOff = Klen; Cp = C1; }
  }
  const int m0 = (CM ? (rem % gx) : (rem / gx)) * 256;
  const int n0 = (CM ? (rem / gx) : (rem % gx)) * 256;

  const int sRow = w * 16 + (lane >> 2);
  const int sSwz = ((lane & 3) ^ ((lane >> 3) & 3)) * 8;
  const short* aG0 = A  + (size_t)(m0 + sRow) * Kpitch + kOff + sSwz;
  const short* aG1 = A  + (size_t)(m0 + 128 + sRow) * Kpitch + kOff + sSwz;
  const short* bG0 = BT + (size_t)(n0 + sRow) * Kpitch + kOff + sSwz;
  const short* bG1 = BT + (size_t)(n0 + 128 + sRow) * Kpitch + kOff + sSwz;

  f32x4 acc[8][4] = {};
  bf16x8 b0 = {}, b1 = {}, b2 = {}, b3 = {};

  STAGE_A_(0, 0, 0) STAGE_A_(0, 1, 0) STAGE_B_(0, 0, 0) STAGE_B_(0, 1, 0)
  STAGE_A_(1, 0, 1) STAGE_B_(1, 0, 1)
  asm volatile("s_waitcnt vmcnt(4)" ::: "memory");
  __builtin_amdgcn_s_barrier();

  const int nIt = Klen >> 7;
  for (int i = 0; i < nIt; ++i) {
    const int c = 2 * i;
    const bool st = (i + 1 < nIt);
    PH_(0, 0, 0, 1, STAGE_A_(1, 1, c + 1))
    PH_(0, 0, 1, 0, STAGE_B_(1, 1, c + 1))
    PH_(0, 1, 0, 1, if (st) STAGE_A_(0, 0, c + 2))
    PH_(0, 1, 1, 0, if (st) STAGE_B_(0, 0, c + 2) VM4)
    PH_(1, 0, 0, 1, if (st) STAGE_A_(0, 1, c + 2))
    PH_(1, 0, 1, 0, if (st) STAGE_B_(0, 1, c + 2))
    PH_(1, 1, 0, 1, if (st) STAGE_A_(1, 0, c + 3))
    PH_(1, 1, 1, 0, if (st) STAGE_B_(1, 0, c + 3) VM4)
  }

  // ---- epilogue: LDS transpose (4 chunks of 64 rows x 256 cols, pitch 260) ----
  float* Cl = (float*)SMEM;
  const int g = lane >> 4;
  #pragma unroll
  for (int ch = 0; ch < 4; ++ch) {
    if (wm == (ch >> 1)) {
      #pragma unroll
      for (int ii2 = 0; ii2 < 4; ++ii2)
        #pragma unroll
        for (int j = 0; j < 4; ++j)
          #pragma unroll
          for (int r = 0; r < 4; ++r)
            Cl[(ii2*16 + g*4 + r) * 260 + wn*64 + j*16 + l15] = acc[(ch & 1)*4 + ii2][j][r];
    }
    asm volatile("s_waitcnt lgkmcnt(0)" ::: "memory");
    __builtin_amdgcn_s_barrier();
    #pragma unroll
    for (int p = 0; p < 4; ++p) {
      const int row = (t >> 5) + p * 16;
      const int c8 = (t & 31) * 8;
      f32x4 v0 = *(const f32x4*)&Cl[row * 260 + c8];
      f32x4 v1 = *(const f32x4*)&Cl[row * 260 + c8 + 4];
      const int grow = m0 + ch * 64 + row;
      if (OUTF32) {
        *(f32x4*)&((float*)Cp)[(size_t)grow * N + n0 + c8]     = v0;
        *(f32x4*)&((float*)Cp)[(size_t)grow * N + n0 + c8 + 4] = v1;
      } else {
        unsigned d0, d1, d2, d3;
        asm("v_cvt_pk_bf16_f32 %0, %1, %2" : "=v"(d0) : "v"(v0[0]), "v"(v0[1]));
        asm("v_cvt_pk_bf16_f32 %0, %1, %2" : "=v"(d1) : "v"(v0[2]), "v"(v0[3]));
        asm("v_cvt_pk_bf16_f32 %0, %1, %2" : "=v"(d2) : "v"(v1[0]), "v"(v1[1]));
        asm("v_cvt_pk_bf16_f32 %0, %1, %2" : "=v"(d3) : "v"(v1[2]), "v"(v1[3]));
        uint4 u = {d0, d1, d2, d3};
        *(uint4*)&((short*)Cp)[(size_t)grow * N + n0 + c8] = u;
      }
    }
    asm volatile("s_waitcnt lgkmcnt(0)" ::: "memory");
    __builtin_amdgcn_s_barrier();
  }
}
#undef As
#undef Bs

// ---------------- per-token: RMSNorm(q,k), gates, partial RoPE, in place ----------------
__global__ __launch_bounds__(256) void k_post(short* __restrict__ Ycat,
    const float* __restrict__ cosb, const float* __restrict__ sinb,
    const float* __restrict__ qw, const float* __restrict__ kw)
{
  const int tok = blockIdx.x;                 // b*S + s
  const int lane = threadIdx.x & 63, w = threadIdx.x >> 6;
  const size_t rowb = (size_t)tok * LW;
  const int d0 = lane * 4;

  float gq[4], gv[4];
  {
    s16x4 a  = *(const s16x4*)&Ycat[rowb + 10240 + d0];
    s16x4 bq = *(const s16x4*)&Ycat[rowb + 10240 + 256 + d0];
    #pragma unroll
    for (int j = 0; j < 4; ++j){ gq[j] = sigm(bf2f(a[j])); gv[j] = sigm(bf2f(bq[j])); }
  }
  float c4[4] = {0,0,0,0}, s4[4] = {0,0,0,0};
  if (lane < 16) {
    float4 c = *(const float4*)&cosb[(size_t)tok * 64 + d0];
    float4 s = *(const float4*)&sinb[(size_t)tok * 64 + d0];
    c4[0]=c.x; c4[1]=c.y; c4[2]=c.z; c4[3]=c.w;
    s4[0]=s.x; s4[1]=s.y; s4[2]=s.z; s4[3]=s.w;
  }
  float4 qv4 = *(const float4*)&qw[d0];
  float4 kv4 = *(const float4*)&kw[d0];
  float qwa[4] = {qv4.x, qv4.y, qv4.z, qv4.w};
  float kwa[4] = {kv4.x, kv4.y, kv4.z, kv4.w};

  #pragma unroll
  for (int hi = 0; hi < 4; ++hi) {
    const int hh = w * 4 + hi;
    const size_t off = rowb + hh * 512 + d0;
    s16x4 v = *(const s16x4*)&Ycat[off];
    float x[4];
    #pragma unroll
    for (int j = 0; j < 4; ++j) x[j] = bf2f(v[j]);
    float ss = x[0]*x[0] + x[1]*x[1] + x[2]*x[2] + x[3]*x[3];
    #pragma unroll
    for (int o2 = 1; o2 < 64; o2 <<= 1) ss += __shfl_xor(ss, o2);
    float rr = rsqrtf(ss * (1.0f/256.0f) + 1e-6f);
    #pragma unroll
    for (int j = 0; j < 4; ++j) x[j] = x[j] * rr * (1.0f + qwa[j]) * gq[j];
    float p[4];
    #pragma unroll
    for (int j = 0; j < 4; ++j) p[j] = __shfl_xor(x[j], 8);
    if (lane < 8)       { for (int j = 0; j < 4; ++j) x[j] = x[j]*c4[j] - p[j]*s4[j]; }
    else if (lane < 16) { for (int j = 0; j < 4; ++j) x[j] = x[j]*c4[j] + p[j]*s4[j]; }
    s16x4 o;
    #pragma unroll
    for (int j = 0; j < 4; ++j) o[j] = f2bf(x[j]);
    *(s16x4*)&Ycat[off] = o;
  }
  {
    const size_t off = rowb + 8192 + w * 256 + d0;
    s16x4 v = *(const s16x4*)&Ycat[off];
    float x[4];
    #pragma unroll
    for (int j = 0; j < 4; ++j) x[j] = bf2f(v[j]);
    float ss = x[0]*x[0] + x[1]*x[1] + x[2]*x[2] + x[3]*x[3];
    #pragma unroll
    for (int o2 = 1; o2 < 64; o2 <<= 1) ss += __shfl_xor(ss, o2);
    float rr = rsqrtf(ss * (1.0f/256.0f) + 1e-6f);
    #pragma unroll
    for (int j = 0; j < 4; ++j) x[j] = x[j] * rr * (1.0f + kwa[j]) * gq[j];
    float p[4];
    #pragma unroll
    for (int j = 0; j < 4; ++j) p[j] = __shfl_xor(x[j], 8);
    if (lane < 8)       { for (int j = 0; j < 4; ++j) x[j] = x[j]*c4[j] - p[j]*s4[j]; }
    else if (lane < 16) { for (int j = 0; j < 4; ++j) x[j] = x[j]*c4[j] + p[j]*s4[j]; }
    s16x4 o;
    #pragma unroll
    for (int j = 0; j < 4; ++j) o[j] = f2bf(x[j]);
    *(s16x4*)&Ycat[off] = o;
  }
  {
    const size_t off = rowb + 9216 + w * 256 + d0;
    s16x4 v = *(const s16x4*)&Ycat[off];
    s16x4 o;
    #pragma unroll
    for (int j = 0; j < 4; ++j) o[j] = f2bf(bf2f(v[j]) * gv[j]);
    *(s16x4*)&Ycat[off] = o;
  }
}

// ====== flash attention v5: v3 structure + K-row permutation -> in-register P ======
// K staged with source-row bijection: LDS row rho holds key j(rho) =
// 8*((rho>>2)&3) + 4*(rho>>4) + (rho&3), so after swapped QK^T each lane's 8
// P values are keys 8g..8g+7 = exactly its PV B-fragment (element-e pairing
// with vf is sigma-insensitive). P never touches LDS.
#define JR(ri) (8 * (((ri)*2 + (tr >> 2)) & 3) + 4 * ((ri) >> 1) + (tr & 3))
#define ATT_STAGE(bb, jj) { \
  _Pragma("unroll") \
  for (int ri = 0; ri < 4; ++ri) \
    gload16(kSrc + (size_t)((jj) + JR(ri)) * LW, &Ks[bb][t*8 + ri*2048]); \
  _Pragma("unroll") \
  for (int ri = 0; ri < 4; ++ri) \
    gload16(vSrc + (jj) + (size_t)(ri*64) * S_LEN, &Vs[bb][t*8 + ri*2048]); }

__global__ __launch_bounds__(256) void k_attn(const short* __restrict__ Ycat,
                                              const short* __restrict__ VT,
                                              short* __restrict__ AO)
{
  __shared__ __align__(16) short Ks[2][8192];   // [buf][32 rows x 256] (rows permuted)
  __shared__ __align__(16) short Vs[2][8192];   // [buf][256 rows x 32]

  const int t = threadIdx.x, lane = t & 63, w = t >> 6;
  const int l15 = lane & 15, g = lane >> 4;
  const int id = blockIdx.x;
  const int xcd = id & 7, widx = id >> 3;
  const int b = xcd >> 2, hk = xcd & 3;
  const int h = hk * 4 + (widx & 3);
  const int x = widx >> 2, qq = x & 7, jj = x >> 3;
  const int qsel = (jj == 0) ? 31 - qq : (jj == 1) ? 16 + qq : (jj == 2) ? 15 - qq : qq;
  const int q0 = qsel * 64;
  const int qg = q0 + w * 16 + l15;        // this lane's q-row (global)
  const float SC2 = 0.09016844f;           // 1/16 * log2(e)

  bf16x8 qf[8];
  {
    const size_t qb = ((size_t)(b * S_LEN) + qg) * LW + h * 512 + g * 8;
    #pragma unroll
    for (int kk = 0; kk < 8; ++kk)
      qf[kk] = *(const bf16x8*)&Ycat[qb + kk * 32];
  }
  asm volatile("s_waitcnt vmcnt(0)" ::: "memory");

  const int tr = t >> 5;                   // LDS K row (mod 8), swizzle-invariant
  const int kColS = ((((t & 31) * 16) ^ (tr << 4)) >> 1);
  const int vRow = t >> 2;
  const int vColS = ((((t & 3) * 16) ^ ((vRow & 3) << 4)) >> 1);
  const short* kSrc = Ycat + (size_t)(b * S_LEN) * LW + 8192 + hk * 256 + kColS;
  const short* vSrc = VT + ((size_t)((b * NKV + hk) * HDIM + vRow)) * S_LEN + vColS;

  f32x4 oacc[16] = {};
  float m_r = -1e30f, l_r = 0.0f;

  const int nt = (q0 >> 5) + 2;
  ATT_STAGE(0, 0)
  int buf = 0;

  for (int ti = 0; ti < nt; ++ti) {
    const int j0 = ti * 32;
    const int jn = (ti + 1 < nt) ? j0 + 32 : 0;   // dummy re-stage keeps vmcnt uniform
    ATT_STAGE(buf ^ 1, jn)
    asm volatile("s_waitcnt vmcnt(8)" ::: "memory");
    __builtin_amdgcn_s_barrier();

    if (j0 <= q0 + w * 16 + 15) {                 // wave-uniform causal skip
      // QK^T swapped; permuted rows => lane's sa[c][r] = S[key j0+8g+4c+r, q=l15]
      f32x4 sa[2] = {};
      #pragma unroll
      for (int kk = 0; kk < 8; ++kk) {
        #pragma unroll
        for (int c = 0; c < 2; ++c) {
          const int row = c * 16 + l15;
          bf16x8 kf = *(const bf16x8*)((const char*)Ks[buf] + row * 512
                       + ((kk * 64 + g * 16) ^ ((l15 & 7) << 4)));
          sa[c] = __builtin_amdgcn_mfma_f32_16x16x32_bf16(kf, qf[kk], sa[c], 0, 0, 0);
        }
      }
      float s[8];
      #pragma unroll
      for (int c = 0; c < 2; ++c)
        #pragma unroll
        for (int r = 0; r < 4; ++r) s[c * 4 + r] = sa[c][r];
      if (j0 + 31 > qg) {
        #pragma unroll
        for (int c = 0; c < 2; ++c)
          #pragma unroll
          for (int r = 0; r < 4; ++r)
            if (j0 + 8 * g + 4 * c + r > qg) s[c * 4 + r] = -1e30f;
      }
      float mx = s[0];
      #pragma unroll
      for (int i = 1; i < 8; ++i) mx = fmaxf(mx, s[i]);
      mx = fmaxf(mx, __shfl_xor(mx, 16));
      mx = fmaxf(mx, __shfl_xor(mx, 32));
      if (!__all(mx - m_r <= 128.0f)) {           // T13 defer-max
        const float mnew = fmaxf(m_r, mx);
        const float alpha = exp2f((m_r - mnew) * SC2);
        l_r *= alpha;
        #pragma unroll
        for (int jb = 0; jb < 16; ++jb)
          #pragma unroll
          for (int r = 0; r < 4; ++r) oacc[jb][r] *= alpha;
        m_r = mnew;
      }
      float p[8], rs = 0.0f;
      #pragma unroll
      for (int i = 0; i < 8; ++i) { p[i] = exp2f((s[i] - m_r) * SC2); rs += p[i]; }
      rs += __shfl_xor(rs, 16);
      rs += __shfl_xor(rs, 32);
      l_r += rs;
      // in-register P -> PV B-fragment (keys 8g..8g+7 in order; pairs lo/hi)
      union { uint4 u; bf16x8 v; } pk;
      asm("v_cvt_pk_bf16_f32 %0, %1, %2" : "=v"(pk.u.x) : "v"(p[0]), "v"(p[1]));
      asm("v_cvt_pk_bf16_f32 %0, %1, %2" : "=v"(pk.u.y) : "v"(p[2]), "v"(p[3]));
      asm("v_cvt_pk_bf16_f32 %0, %1, %2" : "=v"(pk.u.z) : "v"(p[4]), "v"(p[5]));
      asm("v_cvt_pk_bf16_f32 %0, %1, %2" : "=v"(pk.u.w) : "v"(p[6]), "v"(p[7]));
      const bf16x8 pa = pk.v;
      #pragma unroll
      for (int jb = 0; jb < 16; ++jb) {
        const int vrow = jb * 16 + l15;
        bf16x8 vf = *(const bf16x8*)((const char*)Vs[buf] + vrow * 64
                     + ((16 * g) ^ ((l15 & 3) << 4)));
        oacc[jb] = __builtin_amdgcn_mfma_f32_16x16x32_bf16(vf, pa, oacc[jb], 0, 0, 0);
      }
    }
    __builtin_amdgcn_s_barrier();
    buf ^= 1;
  }
  asm volatile("s_waitcnt vmcnt(0)" ::: "memory");  // drain dummy stage

  const float linv = 1.0f / l_r;
  const size_t gb = ((size_t)(b * S_LEN) + qg) * LW + h * 512 + 256;
  const size_t ob = ((size_t)(b * S_LEN) + qg) * 4096 + h * 256;
  #pragma unroll
  for (int jb = 0; jb < 16; ++jb) {
    const int d0 = jb * 16 + g * 4;
    s16x4 gt = *(const s16x4*)&Ycat[gb + d0];
    s16x4 o;
    #pragma unroll
    for (int r = 0; r < 4; ++r)
      o[r] = f2bf(oacc[jb][r] * linv * sigm(bf2f(gt[r])));
    *(s16x4*)&AO[ob + d0] = o;
  }
}

extern "C" void kernel_launch(void* const* d_in, const int* in_sizes, int n_in,
                              void* d_out, int out_size, void* d_ws, size_t ws_size,
                              hipStream_t stream) {
  const float* X    = (const float*)d_in[0];
  const float* cosb = (const float*)d_in[1];
  const float* sinb = (const float*)d_in[2];
  const float* Wq   = (const float*)d_in[4];
  const float* Wk   = (const float*)d_in[5];
  const float* Wv   = (const float*)d_in[6];
  const float* Wo   = (const float*)d_in[7];
  const float* qw   = (const float*)d_in[8];
  const float* kw   = (const float*)d_in[9];
  const float* Wr   = (const float*)d_in[10];

  short* Xb    = (short*)d_ws;                       //  8,388,608
  short* WcatT = Xb    +  8388608;                   // 22,020,096
  short* AO    = WcatT;                              // alias (dead after GEMM0)
  short* WoT   = WcatT + 22020096;                   //  8,388,608
  short* Ycat  = WoT   +  8388608;                   // 44,040,192
  short* VT    = Ycat  + 44040192;                   //  4,194,304
  float* P1    = (float*)Ycat;                       // split-K partial (Ycat dead then)

  dim3 tb(32, 8);
  k_cvt<<<8192, 256, 0, stream>>>(X, Xb, 2097152);
  k_wt<<<7424, 256, 0, stream>>>(Wq, Wk, Wv, Wr, Wo, WcatT, WoT);   // R8 bug: was 5888

  k_gemm2<0, 1, 0><<<672, 512, 0, stream>>>(Xb, WcatT, Ycat, nullptr,
                                            4096, 10752, 2048, 2048, 16);
  k_post<<<4096, 256, 0, stream>>>(Ycat, cosb, sinb, qw, kw);
  k_vt<<<dim3(64, 8, 8), tb, 0, stream>>>(Ycat, VT);
  k_attn<<<1024, 256, 0, stream>>>(Ycat, VT, AO);
  k_gemm2<1, 0, 1><<<256, 512, 0, stream>>>(AO, WoT, d_out, P1,
                                            4096, 2048, 4096, 2048, 8);
  // d_out has 4096*2048 = 8,388,608 floats = 2,097,152 float4s
  k_add<<<2048, 256, 0, stream>>>(P1, (float*)d_out, 2097152);
}

// Round 11
// 456.532 us; speedup vs baseline: 1.1188x; 1.0488x over previous
//
#include <hip/hip_runtime.h>

#define S_LEN 2048
#define NB    2
#define NH    16
#define NKV   4
#define HDIM  256
#define LW    10752   // Ycat row width: 8192 (q|gate) + 1024 (k) + 1024 (v) + 512 (r)

using bf16x8 = __attribute__((ext_vector_type(8))) short;
using s16x4  = __attribute__((ext_vector_type(4))) short;
using f32x4  = __attribute__((ext_vector_type(4))) float;

__device__ __forceinline__ float bf2f(short u){
  union { float f; unsigned u; } x; x.u = ((unsigned)(unsigned short)u) << 16; return x.f;
}
__device__ __forceinline__ short f2bf(float f){
  unsigned i = __builtin_bit_cast(unsigned, f);
  unsigned r = (i + 0x7fffu + ((i >> 16) & 1u)) >> 16;
  return (short)r;
}
__device__ __forceinline__ float sigm(float x){ return 1.0f / (1.0f + __expf(-x)); }

__device__ __forceinline__ void gload16(const short* g, short* lds){
  __builtin_amdgcn_global_load_lds((const __attribute__((address_space(1))) void*)g,
                                   (__attribute__((address_space(3))) void*)lds,
                                   16, 0, 0);
}

// ---------------- split-K reduce: o += b (n4 = float4 count!) ----------------
__global__ void k_add(const float* __restrict__ b, float* __restrict__ o, int n4){
  int i = blockIdx.x * blockDim.x + threadIdx.x;
  const int stride = gridDim.x * blockDim.x;
  for (; i < n4; i += stride) {
    float4 x = ((const float4*)o)[i];
    float4 y = ((const float4*)b)[i];
    float4 z = {x.x + y.x, x.y + y.y, x.z + y.z, x.w + y.w};
    ((float4*)o)[i] = z;
  }
}

// ---- fused weight transpose+convert + X f32->bf16 convert, one launch ----
// ids: Wq [0,4096) | Wk [4096,4608) | Wv [4608,5120) | Wr [5120,5376) |
//      Wo [5376,7424) | X-cvt [7424,15616)   => grid 15616
__global__ __launch_bounds__(256) void k_wt(const float* __restrict__ X,
                     const float* __restrict__ Wq,
                     const float* __restrict__ Wk, const float* __restrict__ Wv,
                     const float* __restrict__ Wr, const float* __restrict__ Wo,
                     short* __restrict__ Xb,
                     short* __restrict__ WcatT, short* __restrict__ WoT)
{
  __shared__ float tile[64][65];
  const int id = blockIdx.x;
  if (id >= 7424) {                      // X convert: 8192 blocks x 256 float4
    const int t = threadIdx.y * 32 + threadIdx.x;
    const int i = (id - 7424) * 256 + t;
    float4 v = ((const float4*)X)[i];
    s16x4 o;
    o[0] = f2bf(v.x); o[1] = f2bf(v.y); o[2] = f2bf(v.z); o[3] = f2bf(v.w);
    ((s16x4*)Xb)[i] = o;
    return;
  }
  const float* src; short* dst; int R, C, Ct, local;
  if (id < 4096)      { src = Wq; dst = WcatT;                      R = 2048; C = 8192; Ct = 128; local = id; }
  else if (id < 4608) { src = Wk; dst = WcatT + (size_t)8192*2048;  R = 2048; C = 1024; Ct =  16; local = id - 4096; }
  else if (id < 5120) { src = Wv; dst = WcatT + (size_t)9216*2048;  R = 2048; C = 1024; Ct =  16; local = id - 4608; }
  else if (id < 5376) { src = Wr; dst = WcatT + (size_t)10240*2048; R = 2048; C =  512; Ct =   8; local = id - 5120; }
  else                { src = Wo; dst = WoT;                        R = 4096; C = 2048; Ct =  32; local = id - 5376; }
  const int c0 = (local % Ct) * 64, r0 = (local / Ct) * 64;
  const int t = threadIdx.y * 32 + threadIdx.x;
  const int rr = t >> 2, cg = (t & 3) * 16;
  #pragma unroll
  for (int j = 0; j < 4; ++j)
    *(float4*)&tile[rr][cg + j*4] = *(const float4*)&src[(size_t)(r0 + rr) * C + c0 + cg + j*4];
  __syncthreads();
  unsigned u[8];
  #pragma unroll
  for (int j = 0; j < 8; ++j) {
    float lo = tile[cg + 2*j][rr], hi = tile[cg + 2*j + 1][rr];
    asm("v_cvt_pk_bf16_f32 %0, %1, %2" : "=v"(u[j]) : "v"(lo), "v"(hi));
  }
  uint4 u0 = {u[0], u[1], u[2], u[3]}, u1 = {u[4], u[5], u[6], u[7]};
  short* dp = &dst[(size_t)(c0 + rr) * R + r0 + cg];
  *(uint4*)dp = u0;
  *(uint4*)(dp + 8) = u1;
}

// ---------------- bf16 V-slice transpose: Ycat v -> VT[b,hk,d,s] ----------------
__global__ void k_vt(const short* __restrict__ Ycat, short* __restrict__ VT){
  __shared__ short tile[32][33];
  int b = blockIdx.z >> 2, hk = blockIdx.z & 3;
  int s0 = blockIdx.x * 32, d0 = blockIdx.y * 32;
  int tx = threadIdx.x, ty = threadIdx.y;   // (32, 8)
  #pragma unroll
  for (int i = ty; i < 32; i += 8)
    tile[i][tx] = Ycat[(size_t)(b * S_LEN + s0 + i) * LW + 9216 + hk * 256 + d0 + tx];
  __syncthreads();
  #pragma unroll
  for (int i = ty; i < 32; i += 8)
    VT[(size_t)((b * NKV + hk) * HDIM + d0 + i) * S_LEN + s0 + tx] = tile[tx][i];
}

// ================= 256x256 8-phase bf16 GEMM (T1+T2+T3/T4+T5) =================
#define MFMA_(a, b, c) __builtin_amdgcn_mfma_f32_16x16x32_bf16(a, b, c, 0, 0, 0)
#define As ((short(*)[2][8192])(SMEM))
#define Bs ((short(*)[2][8192])(SMEM + 32768))
#define LDA_(buf, ks, mh, f) (*(const bf16x8*)&As[buf][ks][(wm*128 + (mh)*64 + (f)*16 + l15) * 32 + rdSlot])
#define LDB_(buf, ks, f)     (*(const bf16x8*)&Bs[buf][ks][(wn*64  + (f)*16 + l15) * 32 + rdSlot])
#define STAGE_A_(buf, ks, tile) { \
  gload16(aG0 + (size_t)(tile)*64 + (ks)*32, &As[buf][ks][w*512]); \
  gload16(aG1 + (size_t)(tile)*64 + (ks)*32, &As[buf][ks][4096 + w*512]); }
#define STAGE_B_(buf, ks, tile) { \
  gload16(bG0 + (size_t)(tile)*64 + (ks)*32, &Bs[buf][ks][w*512]); \
  gload16(bG1 + (size_t)(tile)*64 + (ks)*32, &Bs[buf][ks][4096 + w*512]); }
#define VM4 asm volatile("s_waitcnt vmcnt(4)" ::: "memory");
#define PH_(buf, ks, mh, LB, ...) { \
  bf16x8 a0 = LDA_(buf,ks,mh,0), a1 = LDA_(buf,ks,mh,1), a2 = LDA_(buf,ks,mh,2), a3 = LDA_(buf,ks,mh,3); \
  if (LB) { b0 = LDB_(buf,ks,0); b1 = LDB_(buf,ks,1); b2 = LDB_(buf,ks,2); b3 = LDB_(buf,ks,3); } \
  __VA_ARGS__ \
  __builtin_amdgcn_s_barrier(); \
  asm volatile("s_waitcnt lgkmcnt(0)" ::: "memory"); \
  __builtin_amdgcn_s_setprio(1); \
  acc[(mh)*4+0][0] = MFMA_(a0, b0, acc[(mh)*4+0][0]); \
  acc[(mh)*4+0][1] = MFMA_(a0, b1, acc[(mh)*4+0][1]); \
  acc[(mh)*4+0][2] = MFMA_(a0, b2, acc[(mh)*4+0][2]); \
  acc[(mh)*4+0][3] = MFMA_(a0, b3, acc[(mh)*4+0][3]); \
  acc[(mh)*4+1][0] = MFMA_(a1, b0, acc[(mh)*4+1][0]); \
  acc[(mh)*4+1][1] = MFMA_(a1, b1, acc[(mh)*4+1][1]); \
  acc[(mh)*4+1][2] = MFMA_(a1, b2, acc[(mh)*4+1][2]); \
  acc[(mh)*4+1][3] = MFMA_(a1, b3, acc[(mh)*4+1][3]); \
  acc[(mh)*4+2][0] = MFMA_(a2, b0, acc[(mh)*4+2][0]); \
  acc[(mh)*4+2][1] = MFMA_(a2, b1, acc[(mh)*4+2][1]); \
  acc[(mh)*4+2][2] = MFMA_(a2, b2, acc[(mh)*4+2][2]); \
  acc[(mh)*4+2][3] = MFMA_(a2, b3, acc[(mh)*4+2][3]); \
  acc[(mh)*4+3][0] = MFMA_(a3, b0, acc[(mh)*4+3][0]); \
  acc[(mh)*4+3][1] = MFMA_(a3, b1, acc[(mh)*4+3][1]); \
  acc[(mh)*4+3][2] = MFMA_(a3, b2, acc[(mh)*4+3][2]); \
  acc[(mh)*4+3][3] = MFMA_(a3, b3, acc[(mh)*4+3][3]); \
  __builtin_amdgcn_s_setprio(0); \
  __builtin_amdgcn_s_barrier(); }

template<int OUTF32, int CM, int SPLITK>
__global__ __launch_bounds__(512) void k_gemm2(const short* __restrict__ A,
                                               const short* __restrict__ BT,
                                               void* __restrict__ C0,
                                               void* __restrict__ C1,
                                               int M, int N, int Kpitch, int Klen,
                                               int gx)
{
  __shared__ __align__(16) short SMEM[65536];   // As | Bs ; epilogue: fp32 stage
  const int t = threadIdx.x, lane = t & 63, w = t >> 6;
  const int l15 = lane & 15;
  const int wm = w >> 2, wn = w & 3;
  const int rdSlot = (((lane >> 4) ^ ((lane >> 1) & 3)) * 8);

  const int nwg = gridDim.x;
  const int swz = (blockIdx.x & 7) * (nwg >> 3) + (blockIdx.x >> 3);
  int rem = swz, kOff = 0;
  void* Cp = C0;
  if (SPLITK) {                 // nwg == 256: top bit selects K-half
    rem = swz & 127;
    if (swz >> 7) { kOff = Klen; Cp = C1; }
  }
  const int m0 = (CM ? (rem % gx) : (rem / gx)) * 256;
  const int n0 = (CM ? (rem / gx) : (rem % gx)) * 256;

  const int sRow = w * 16 + (lane >> 2);
  const int sSwz = ((lane & 3) ^ ((lane >> 3) & 3)) * 8;
  const short* aG0 = A  + (size_t)(m0 + sRow) * Kpitch + kOff + sSwz;
  const short* aG1 = A  + (size_t)(m0 + 128 + sRow) * Kpitch + kOff + sSwz;
  const short* bG0 = BT + (size_t)(n0 + sRow) * Kpitch + kOff + sSwz;
  const short* bG1 = BT + (size_t)(n0 + 128 + sRow) * Kpitch + kOff + sSwz;

  f32x4 acc[8][4] = {};
  bf16x8 b0 = {}, b1 = {}, b2 = {}, b3 = {};

  STAGE_A_(0, 0, 0) STAGE_A_(0, 1, 0) STAGE_B_(0, 0, 0) STAGE_B_(0, 1, 0)
  STAGE_A_(1, 0, 1) STAGE_B_(1, 0, 1)
  asm volatile("s_waitcnt vmcnt(4)" ::: "memory");
  __builtin_amdgcn_s_barrier();

  const int nIt = Klen >> 7;
  for (int i = 0; i < nIt; ++i) {
    const int c = 2 * i;
    const bool st = (i + 1 < nIt);
    PH_(0, 0, 0, 1, STAGE_A_(1, 1, c + 1))
    PH_(0, 0, 1, 0, STAGE_B_(1, 1, c + 1))
    PH_(0, 1, 0, 1, if (st) STAGE_A_(0, 0, c + 2))
    PH_(0, 1, 1, 0, if (st) STAGE_B_(0, 0, c + 2) VM4)
    PH_(1, 0, 0, 1, if (st) STAGE_A_(0, 1, c + 2))
    PH_(1, 0, 1, 0, if (st) STAGE_B_(0, 1, c + 2))
    PH_(1, 1, 0, 1, if (st) STAGE_A_(1, 0, c + 3))
    PH_(1, 1, 1, 0, if (st) STAGE_B_(1, 0, c + 3) VM4)
  }

  // ---- epilogue: LDS transpose (4 chunks of 64 rows x 256 cols, pitch 260) ----
  float* Cl = (float*)SMEM;
  const int g = lane >> 4;
  #pragma unroll
  for (int ch = 0; ch < 4; ++ch) {
    if (wm == (ch >> 1)) {
      #pragma unroll
      for (int ii2 = 0; ii2 < 4; ++ii2)
        #pragma unroll
        for (int j = 0; j < 4; ++j)
          #pragma unroll
          for (int r = 0; r < 4; ++r)
            Cl[(ii2*16 + g*4 + r) * 260 + wn*64 + j*16 + l15] = acc[(ch & 1)*4 + ii2][j][r];
    }
    asm volatile("s_waitcnt lgkmcnt(0)" ::: "memory");
    __builtin_amdgcn_s_barrier();
    #pragma unroll
    for (int p = 0; p < 4; ++p) {
      const int row = (t >> 5) + p * 16;
      const int c8 = (t & 31) * 8;
      f32x4 v0 = *(const f32x4*)&Cl[row * 260 + c8];
      f32x4 v1 = *(const f32x4*)&Cl[row * 260 + c8 + 4];
      const int grow = m0 + ch * 64 + row;
      if (OUTF32) {
        *(f32x4*)&((float*)Cp)[(size_t)grow * N + n0 + c8]     = v0;
        *(f32x4*)&((float*)Cp)[(size_t)grow * N + n0 + c8 + 4] = v1;
      } else {
        unsigned d0, d1, d2, d3;
        asm("v_cvt_pk_bf16_f32 %0, %1, %2" : "=v"(d0) : "v"(v0[0]), "v"(v0[1]));
        asm("v_cvt_pk_bf16_f32 %0, %1, %2" : "=v"(d1) : "v"(v0[2]), "v"(v0[3]));
        asm("v_cvt_pk_bf16_f32 %0, %1, %2" : "=v"(d2) : "v"(v1[0]), "v"(v1[1]));
        asm("v_cvt_pk_bf16_f32 %0, %1, %2" : "=v"(d3) : "v"(v1[2]), "v"(v1[3]));
        uint4 u = {d0, d1, d2, d3};
        *(uint4*)&((short*)Cp)[(size_t)grow * N + n0 + c8] = u;
      }
    }
    asm volatile("s_waitcnt lgkmcnt(0)" ::: "memory");
    __builtin_amdgcn_s_barrier();
  }
}
#undef As
#undef Bs

// ---------------- per-token: RMSNorm(q,k), gates, partial RoPE, in place ----------------
__global__ __launch_bounds__(256) void k_post(short* __restrict__ Ycat,
    const float* __restrict__ cosb, const float* __restrict__ sinb,
    const float* __restrict__ qw, const float* __restrict__ kw)
{
  const int tok = blockIdx.x;                 // b*S + s
  const int lane = threadIdx.x & 63, w = threadIdx.x >> 6;
  const size_t rowb = (size_t)tok * LW;
  const int d0 = lane * 4;

  float gq[4], gv[4];
  {
    s16x4 a  = *(const s16x4*)&Ycat[rowb + 10240 + d0];
    s16x4 bq = *(const s16x4*)&Ycat[rowb + 10240 + 256 + d0];
    #pragma unroll
    for (int j = 0; j < 4; ++j){ gq[j] = sigm(bf2f(a[j])); gv[j] = sigm(bf2f(bq[j])); }
  }
  float c4[4] = {0,0,0,0}, s4[4] = {0,0,0,0};
  if (lane < 16) {
    float4 c = *(const float4*)&cosb[(size_t)tok * 64 + d0];
    float4 s = *(const float4*)&sinb[(size_t)tok * 64 + d0];
    c4[0]=c.x; c4[1]=c.y; c4[2]=c.z; c4[3]=c.w;
    s4[0]=s.x; s4[1]=s.y; s4[2]=s.z; s4[3]=s.w;
  }
  float4 qv4 = *(const float4*)&qw[d0];
  float4 kv4 = *(const float4*)&kw[d0];
  float qwa[4] = {qv4.x, qv4.y, qv4.z, qv4.w};
  float kwa[4] = {kv4.x, kv4.y, kv4.z, kv4.w};

  #pragma unroll
  for (int hi = 0; hi < 4; ++hi) {
    const int hh = w * 4 + hi;
    const size_t off = rowb + hh * 512 + d0;
    s16x4 v = *(const s16x4*)&Ycat[off];
    float x[4];
    #pragma unroll
    for (int j = 0; j < 4; ++j) x[j] = bf2f(v[j]);
    float ss = x[0]*x[0] + x[1]*x[1] + x[2]*x[2] + x[3]*x[3];
    #pragma unroll
    for (int o2 = 1; o2 < 64; o2 <<= 1) ss += __shfl_xor(ss, o2);
    float rr = rsqrtf(ss * (1.0f/256.0f) + 1e-6f);
    #pragma unroll
    for (int j = 0; j < 4; ++j) x[j] = x[j] * rr * (1.0f + qwa[j]) * gq[j];
    float p[4];
    #pragma unroll
    for (int j = 0; j < 4; ++j) p[j] = __shfl_xor(x[j], 8);
    if (lane < 8)       { for (int j = 0; j < 4; ++j) x[j] = x[j]*c4[j] - p[j]*s4[j]; }
    else if (lane < 16) { for (int j = 0; j < 4; ++j) x[j] = x[j]*c4[j] + p[j]*s4[j]; }
    s16x4 o;
    #pragma unroll
    for (int j = 0; j < 4; ++j) o[j] = f2bf(x[j]);
    *(s16x4*)&Ycat[off] = o;
  }
  {
    const size_t off = rowb + 8192 + w * 256 + d0;
    s16x4 v = *(const s16x4*)&Ycat[off];
    float x[4];
    #pragma unroll
    for (int j = 0; j < 4; ++j) x[j] = bf2f(v[j]);
    float ss = x[0]*x[0] + x[1]*x[1] + x[2]*x[2] + x[3]*x[3];
    #pragma unroll
    for (int o2 = 1; o2 < 64; o2 <<= 1) ss += __shfl_xor(ss, o2);
    float rr = rsqrtf(ss * (1.0f/256.0f) + 1e-6f);
    #pragma unroll
    for (int j = 0; j < 4; ++j) x[j] = x[j] * rr * (1.0f + kwa[j]) * gq[j];
    float p[4];
    #pragma unroll
    for (int j = 0; j < 4; ++j) p[j] = __shfl_xor(x[j], 8);
    if (lane < 8)       { for (int j = 0; j < 4; ++j) x[j] = x[j]*c4[j] - p[j]*s4[j]; }
    else if (lane < 16) { for (int j = 0; j < 4; ++j) x[j] = x[j]*c4[j] + p[j]*s4[j]; }
    s16x4 o;
    #pragma unroll
    for (int j = 0; j < 4; ++j) o[j] = f2bf(x[j]);
    *(s16x4*)&Ycat[off] = o;
  }
  {
    const size_t off = rowb + 9216 + w * 256 + d0;
    s16x4 v = *(const s16x4*)&Ycat[off];
    s16x4 o;
    #pragma unroll
    for (int j = 0; j < 4; ++j) o[j] = f2bf(bf2f(v[j]) * gv[j]);
    *(s16x4*)&Ycat[off] = o;
  }
}

// ====== flash attention v6: v5 + STATIC-MAX softmax (RMSNorm bounds |s|<=18.3) ======
// softmax is shift-invariant; fixed m=20 => p = exp2(s*SC2 - 1.8034) in [e^-2.4, 1].
// Deletes max-reduce, __all/rescale branch; l deferred to epilogue (2 shfl total).
// Chain per tile: QK -> mask -> 8 exp2 (fmaf) -> 4 cvt_pk -> PV.
#define JR(ri) (8 * (((ri)*2 + (tr >> 2)) & 3) + 4 * ((ri) >> 1) + (tr & 3))
#define ATT_STAGE(bb, jj) { \
  _Pragma("unroll") \
  for (int ri = 0; ri < 4; ++ri) \
    gload16(kSrc + (size_t)((jj) + JR(ri)) * LW, &Ks[bb][t*8 + ri*2048]); \
  _Pragma("unroll") \
  for (int ri = 0; ri < 4; ++ri) \
    gload16(vSrc + (jj) + (size_t)(ri*64) * S_LEN, &Vs[bb][t*8 + ri*2048]); }

__global__ __launch_bounds__(256) void k_attn(const short* __restrict__ Ycat,
                                              const short* __restrict__ VT,
                                              short* __restrict__ AO)
{
  __shared__ __align__(16) short Ks[2][8192];   // [buf][32 rows x 256] (rows permuted)
  __shared__ __align__(16) short Vs[2][8192];   // [buf][256 rows x 32]

  const int t = threadIdx.x, lane = t & 63, w = t >> 6;
  const int l15 = lane & 15, g = lane >> 4;
  const int id = blockIdx.x;
  const int xcd = id & 7, widx = id >> 3;
  const int b = xcd >> 2, hk = xcd & 3;
  const int h = hk * 4 + (widx & 3);
  const int x = widx >> 2, qq = x & 7, jj = x >> 3;
  const int qsel = (jj == 0) ? 31 - qq : (jj == 1) ? 16 + qq : (jj == 2) ? 15 - qq : qq;
  const int q0 = qsel * 64;
  const int qg = q0 + w * 16 + l15;        // this lane's q-row (global)
  const float SC2 = 0.09016844f;           // 1/16 * log2(e)
  const float MSH = 1.8033688f;            // 20 * SC2 (static max shift)

  bf16x8 qf[8];
  {
    const size_t qb = ((size_t)(b * S_LEN) + qg) * LW + h * 512 + g * 8;
    #pragma unroll
    for (int kk = 0; kk < 8; ++kk)
      qf[kk] = *(const bf16x8*)&Ycat[qb + kk * 32];
  }
  asm volatile("s_waitcnt vmcnt(0)" ::: "memory");

  const int tr = t >> 5;                   // LDS K row (mod 8), swizzle-invariant
  const int kColS = ((((t & 31) * 16) ^ (tr << 4)) >> 1);
  const int vRow = t >> 2;
  const int vColS = ((((t & 3) * 16) ^ ((vRow & 3) << 4)) >> 1);
  const short* kSrc = Ycat + (size_t)(b * S_LEN) * LW + 8192 + hk * 256 + kColS;
  const short* vSrc = VT + ((size_t)((b * NKV + hk) * HDIM + vRow)) * S_LEN + vColS;

  f32x4 oacc[16] = {};
  float l_r = 0.0f;                        // per-lane partial (8 keys/tile)

  const int nt = (q0 >> 5) + 2;
  ATT_STAGE(0, 0)
  int buf = 0;

  for (int ti = 0; ti < nt; ++ti) {
    const int j0 = ti * 32;
    const int jn = (ti + 1 < nt) ? j0 + 32 : 0;   // dummy re-stage keeps vmcnt uniform
    ATT_STAGE(buf ^ 1, jn)
    asm volatile("s_waitcnt vmcnt(8)" ::: "memory");
    __builtin_amdgcn_s_barrier();

    if (j0 <= q0 + w * 16 + 15) {                 // wave-uniform causal skip
      // QK^T swapped; permuted rows => lane's sa[c][r] = S[key j0+8g+4c+r, q=l15]
      f32x4 sa[2] = {};
      #pragma unroll
      for (int kk = 0; kk < 8; ++kk) {
        #pragma unroll
        for (int c = 0; c < 2; ++c) {
          const int row = c * 16 + l15;
          bf16x8 kf = *(const bf16x8*)((const char*)Ks[buf] + row * 512
                       + ((kk * 64 + g * 16) ^ ((l15 & 7) << 4)));
          sa[c] = __builtin_amdgcn_mfma_f32_16x16x32_bf16(kf, qf[kk], sa[c], 0, 0, 0);
        }
      }
      float s[8];
      #pragma unroll
      for (int c = 0; c < 2; ++c)
        #pragma unroll
        for (int r = 0; r < 4; ++r) s[c * 4 + r] = sa[c][r];
      if (j0 + 31 > qg) {
        #pragma unroll
        for (int c = 0; c < 2; ++c)
          #pragma unroll
          for (int r = 0; r < 4; ++r)
            if (j0 + 8 * g + 4 * c + r > qg) s[c * 4 + r] = -1e30f;
      }
      // static-max softmax: p = exp2(s*SC2 - MSH); masked -> exp2(-9e28) = 0
      float p[8];
      #pragma unroll
      for (int i = 0; i < 8; ++i) { p[i] = exp2f(fmaf(s[i], SC2, -MSH)); l_r += p[i]; }
      // in-register P -> PV B-fragment (keys 8g..8g+7 in order; pairs lo/hi)
      union { uint4 u; bf16x8 v; } pk;
      asm("v_cvt_pk_bf16_f32 %0, %1, %2" : "=v"(pk.u.x) : "v"(p[0]), "v"(p[1]));
      asm("v_cvt_pk_bf16_f32 %0, %1, %2" : "=v"(pk.u.y) : "v"(p[2]), "v"(p[3]));
      asm("v_cvt_pk_bf16_f32 %0, %1, %2" : "=v"(pk.u.z) : "v"(p[4]), "v"(p[5]));
      asm("v_cvt_pk_bf16_f32 %0, %1, %2" : "=v"(pk.u.w) : "v"(p[6]), "v"(p[7]));
      const bf16x8 pa = pk.v;
      #pragma unroll
      for (int jb = 0; jb < 16; ++jb) {
        const int vrow = jb * 16 + l15;
        bf16x8 vf = *(const bf16x8*)((const char*)Vs[buf] + vrow * 64
                     + ((16 * g) ^ ((l15 & 3) << 4)));
        oacc[jb] = __builtin_amdgcn_mfma_f32_16x16x32_bf16(vf, pa, oacc[jb], 0, 0, 0);
      }
    }
    __builtin_amdgcn_s_barrier();
    buf ^= 1;
  }
  asm volatile("s_waitcnt vmcnt(0)" ::: "memory");  // drain dummy stage

  // deferred row-sum: 4 lane-groups hold disjoint key partials of the same q-row
  float l = l_r;
  l += __shfl_xor(l, 16);
  l += __shfl_xor(l, 32);
  const float linv = 1.0f / l;
  const size_t gb = ((size_t)(b * S_LEN) + qg) * LW + h * 512 + 256;
  const size_t ob = ((size_t)(b * S_LEN) + qg) * 4096 + h * 256;
  #pragma unroll
  for (int jb = 0; jb < 16; ++jb) {
    const int d0 = jb * 16 + g * 4;
    s16x4 gt = *(const s16x4*)&Ycat[gb + d0];
    s16x4 o;
    #pragma unroll
    for (int r = 0; r < 4; ++r)
      o[r] = f2bf(oacc[jb][r] * linv * sigm(bf2f(gt[r])));
    *(s16x4*)&AO[ob + d0] = o;
  }
}

extern "C" void kernel_launch(void* const* d_in, const int* in_sizes, int n_in,
                              void* d_out, int out_size, void* d_ws, size_t ws_size,
                              hipStream_t stream) {
  const float* X    = (const float*)d_in[0];
  const float* cosb = (const float*)d_in[1];
  const float* sinb = (const float*)d_in[2];
  const float* Wq   = (const float*)d_in[4];
  const float* Wk   = (const float*)d_in[5];
  const float* Wv   = (const float*)d_in[6];
  const float* Wo   = (const float*)d_in[7];
  const float* qw   = (const float*)d_in[8];
  const float* kw   = (const float*)d_in[9];
  const float* Wr   = (const float*)d_in[10];

  short* Xb    = (short*)d_ws;                       //  8,388,608
  short* WcatT = Xb    +  8388608;                   // 22,020,096
  short* AO    = WcatT;                              // alias (dead after GEMM0)
  short* WoT   = WcatT + 22020096;                   //  8,388,608
  short* Ycat  = WoT   +  8388608;                   // 44,040,192
  short* VT    = Ycat  + 44040192;                   //  4,194,304
  float* P1    = (float*)Ycat;                       // split-K partial (Ycat dead then)

  dim3 tb(32, 8);
  // fused: weight transposes (7424 tiles) + X convert (8192 chunks) = 15616
  k_wt<<<15616, tb, 0, stream>>>(X, Wq, Wk, Wv, Wr, Wo, Xb, WcatT, WoT);

  k_gemm2<0, 1, 0><<<672, 512, 0, stream>>>(Xb, WcatT, Ycat, nullptr,
                                            4096, 10752, 2048, 2048, 16);
  k_post<<<4096, 256, 0, stream>>>(Ycat, cosb, sinb, qw, kw);
  k_vt<<<dim3(64, 8, 8), tb, 0, stream>>>(Ycat, VT);
  k_attn<<<1024, 256, 0, stream>>>(Ycat, VT, AO);
  k_gemm2<1, 0, 1><<<256, 512, 0, stream>>>(AO, WoT, d_out, P1,
                                            4096, 2048, 4096, 2048, 8);
  // d_out has 4096*2048 = 8,388,608 floats = 2,097,152 float4s
  k_add<<<2048, 256, 0, stream>>>(P1, (float*)d_out, 2097152);
}

// Round 12
// 454.032 us; speedup vs baseline: 1.1250x; 1.0055x over previous
//
#include <hip/hip_runtime.h>

#define S_LEN 2048
#define NB    2
#define NH    16
#define NKV   4
#define HDIM  256
#define LW    10752   // Ycat row width: 8192 (q|gate) + 1024 (k) + 1024 (v) + 512 (r)

using bf16x8 = __attribute__((ext_vector_type(8))) short;
using s16x4  = __attribute__((ext_vector_type(4))) short;
using f32x4  = __attribute__((ext_vector_type(4))) float;

__device__ __forceinline__ float bf2f(short u){
  union { float f; unsigned u; } x; x.u = ((unsigned)(unsigned short)u) << 16; return x.f;
}
__device__ __forceinline__ short f2bf(float f){
  unsigned i = __builtin_bit_cast(unsigned, f);
  unsigned r = (i + 0x7fffu + ((i >> 16) & 1u)) >> 16;
  return (short)r;
}
__device__ __forceinline__ float sigm(float x){ return 1.0f / (1.0f + __expf(-x)); }

__device__ __forceinline__ void gload16(const short* g, short* lds){
  __builtin_amdgcn_global_load_lds((const __attribute__((address_space(1))) void*)g,
                                   (__attribute__((address_space(3))) void*)lds,
                                   16, 0, 0);
}

// ---------------- split-K reduce: o += b (n4 = float4 count!) ----------------
__global__ void k_add(const float* __restrict__ b, float* __restrict__ o, int n4){
  int i = blockIdx.x * blockDim.x + threadIdx.x;
  const int stride = gridDim.x * blockDim.x;
  for (; i < n4; i += stride) {
    float4 x = ((const float4*)o)[i];
    float4 y = ((const float4*)b)[i];
    float4 z = {x.x + y.x, x.y + y.y, x.z + y.z, x.w + y.w};
    ((float4*)o)[i] = z;
  }
}

// ---- fused weight transpose+convert + X f32->bf16 convert, one launch ----
// ids: Wq [0,4096) | Wk [4096,4608) | Wv [4608,5120) | Wr [5120,5376) |
//      Wo [5376,7424) | X-cvt [7424,15616)   => grid 15616
__global__ __launch_bounds__(256) void k_wt(const float* __restrict__ X,
                     const float* __restrict__ Wq,
                     const float* __restrict__ Wk, const float* __restrict__ Wv,
                     const float* __restrict__ Wr, const float* __restrict__ Wo,
                     short* __restrict__ Xb,
                     short* __restrict__ WcatT, short* __restrict__ WoT)
{
  __shared__ float tile[64][65];
  const int id = blockIdx.x;
  if (id >= 7424) {                      // X convert: 8192 blocks x 256 float4
    const int t = threadIdx.y * 32 + threadIdx.x;
    const int i = (id - 7424) * 256 + t;
    float4 v = ((const float4*)X)[i];
    s16x4 o;
    o[0] = f2bf(v.x); o[1] = f2bf(v.y); o[2] = f2bf(v.z); o[3] = f2bf(v.w);
    ((s16x4*)Xb)[i] = o;
    return;
  }
  const float* src; short* dst; int R, C, Ct, local;
  if (id < 4096)      { src = Wq; dst = WcatT;                      R = 2048; C = 8192; Ct = 128; local = id; }
  else if (id < 4608) { src = Wk; dst = WcatT + (size_t)8192*2048;  R = 2048; C = 1024; Ct =  16; local = id - 4096; }
  else if (id < 5120) { src = Wv; dst = WcatT + (size_t)9216*2048;  R = 2048; C = 1024; Ct =  16; local = id - 4608; }
  else if (id < 5376) { src = Wr; dst = WcatT + (size_t)10240*2048; R = 2048; C =  512; Ct =   8; local = id - 5120; }
  else                { src = Wo; dst = WoT;                        R = 4096; C = 2048; Ct =  32; local = id - 5376; }
  const int c0 = (local % Ct) * 64, r0 = (local / Ct) * 64;
  const int t = threadIdx.y * 32 + threadIdx.x;
  const int rr = t >> 2, cg = (t & 3) * 16;
  #pragma unroll
  for (int j = 0; j < 4; ++j)
    *(float4*)&tile[rr][cg + j*4] = *(const float4*)&src[(size_t)(r0 + rr) * C + c0 + cg + j*4];
  __syncthreads();
  unsigned u[8];
  #pragma unroll
  for (int j = 0; j < 8; ++j) {
    float lo = tile[cg + 2*j][rr], hi = tile[cg + 2*j + 1][rr];
    asm("v_cvt_pk_bf16_f32 %0, %1, %2" : "=v"(u[j]) : "v"(lo), "v"(hi));
  }
  uint4 u0 = {u[0], u[1], u[2], u[3]}, u1 = {u[4], u[5], u[6], u[7]};
  short* dp = &dst[(size_t)(c0 + rr) * R + r0 + cg];
  *(uint4*)dp = u0;
  *(uint4*)(dp + 8) = u1;
}

// ---------------- bf16 V-slice transpose: Ycat v -> VT[b,hk,d,s] ----------------
__global__ void k_vt(const short* __restrict__ Ycat, short* __restrict__ VT){
  __shared__ short tile[32][33];
  int b = blockIdx.z >> 2, hk = blockIdx.z & 3;
  int s0 = blockIdx.x * 32, d0 = blockIdx.y * 32;
  int tx = threadIdx.x, ty = threadIdx.y;   // (32, 8)
  #pragma unroll
  for (int i = ty; i < 32; i += 8)
    tile[i][tx] = Ycat[(size_t)(b * S_LEN + s0 + i) * LW + 9216 + hk * 256 + d0 + tx];
  __syncthreads();
  #pragma unroll
  for (int i = ty; i < 32; i += 8)
    VT[(size_t)((b * NKV + hk) * HDIM + d0 + i) * S_LEN + s0 + tx] = tile[tx][i];
}

// ================= 256x256 8-phase bf16 GEMM (T1+T2+T3/T4+T5) =================
// v2: ds_read PREFETCH one phase ahead (cur/next reg sets); counted lgkm waits
// are left to the compiler (no blanket lgkmcnt(0)). P1/P5 load own frags (their
// regions are only guaranteed by the preceding VM4+barrier); P2-4,P6-8 frags
// issue during the previous phase => LDS service overlaps the MFMA windows.
#define MFMA_(a, b, c) __builtin_amdgcn_mfma_f32_16x16x32_bf16(a, b, c, 0, 0, 0)
#define As ((short(*)[2][8192])(SMEM))
#define Bs ((short(*)[2][8192])(SMEM + 32768))
#define LDA_(buf, ks, mh, f) (*(const bf16x8*)&As[buf][ks][(wm*128 + (mh)*64 + (f)*16 + l15) * 32 + rdSlot])
#define LDB_(buf, ks, f)     (*(const bf16x8*)&Bs[buf][ks][(wn*64  + (f)*16 + l15) * 32 + rdSlot])
#define LD_A4(d0,d1,d2,d3, buf,ks,mh) { d0 = LDA_(buf,ks,mh,0); d1 = LDA_(buf,ks,mh,1); \
                                        d2 = LDA_(buf,ks,mh,2); d3 = LDA_(buf,ks,mh,3); }
#define LD_B4(d0,d1,d2,d3, buf,ks)    { d0 = LDB_(buf,ks,0); d1 = LDB_(buf,ks,1); \
                                        d2 = LDB_(buf,ks,2); d3 = LDB_(buf,ks,3); }
#define STAGE_A_(buf, ks, tile) { \
  gload16(aG0 + (size_t)(tile)*64 + (ks)*32, &As[buf][ks][w*512]); \
  gload16(aG1 + (size_t)(tile)*64 + (ks)*32, &As[buf][ks][4096 + w*512]); }
#define STAGE_B_(buf, ks, tile) { \
  gload16(bG0 + (size_t)(tile)*64 + (ks)*32, &Bs[buf][ks][w*512]); \
  gload16(bG1 + (size_t)(tile)*64 + (ks)*32, &Bs[buf][ks][4096 + w*512]); }
#define VM4 asm volatile("s_waitcnt vmcnt(4)" ::: "memory");
#define BAR __builtin_amdgcn_s_barrier();
#define MM16(A0,A1,A2,A3, B0,B1,B2,B3, mh) { \
  __builtin_amdgcn_s_setprio(1); \
  acc[(mh)*4+0][0] = MFMA_(A0, B0, acc[(mh)*4+0][0]); \
  acc[(mh)*4+0][1] = MFMA_(A0, B1, acc[(mh)*4+0][1]); \
  acc[(mh)*4+0][2] = MFMA_(A0, B2, acc[(mh)*4+0][2]); \
  acc[(mh)*4+0][3] = MFMA_(A0, B3, acc[(mh)*4+0][3]); \
  acc[(mh)*4+1][0] = MFMA_(A1, B0, acc[(mh)*4+1][0]); \
  acc[(mh)*4+1][1] = MFMA_(A1, B1, acc[(mh)*4+1][1]); \
  acc[(mh)*4+1][2] = MFMA_(A1, B2, acc[(mh)*4+1][2]); \
  acc[(mh)*4+1][3] = MFMA_(A1, B3, acc[(mh)*4+1][3]); \
  acc[(mh)*4+2][0] = MFMA_(A2, B0, acc[(mh)*4+2][0]); \
  acc[(mh)*4+2][1] = MFMA_(A2, B1, acc[(mh)*4+2][1]); \
  acc[(mh)*4+2][2] = MFMA_(A2, B2, acc[(mh)*4+2][2]); \
  acc[(mh)*4+2][3] = MFMA_(A2, B3, acc[(mh)*4+2][3]); \
  acc[(mh)*4+3][0] = MFMA_(A3, B0, acc[(mh)*4+3][0]); \
  acc[(mh)*4+3][1] = MFMA_(A3, B1, acc[(mh)*4+3][1]); \
  acc[(mh)*4+3][2] = MFMA_(A3, B2, acc[(mh)*4+3][2]); \
  acc[(mh)*4+3][3] = MFMA_(A3, B3, acc[(mh)*4+3][3]); \
  __builtin_amdgcn_s_setprio(0); }

template<int OUTF32, int CM, int SPLITK>
__global__ __launch_bounds__(512) void k_gemm2(const short* __restrict__ A,
                                               const short* __restrict__ BT,
                                               void* __restrict__ C0,
                                               void* __restrict__ C1,
                                               int M, int N, int Kpitch, int Klen,
                                               int gx)
{
  __shared__ __align__(16) short SMEM[65536];   // As | Bs ; epilogue: fp32 stage
  const int t = threadIdx.x, lane = t & 63, w = t >> 6;
  const int l15 = lane & 15;
  const int wm = w >> 2, wn = w & 3;
  const int rdSlot = (((lane >> 4) ^ ((lane >> 1) & 3)) * 8);

  const int nwg = gridDim.x;
  const int swz = (blockIdx.x & 7) * (nwg >> 3) + (blockIdx.x >> 3);
  int rem = swz, kOff = 0;
  void* Cp = C0;
  if (SPLITK) {                 // nwg == 256: top bit selects K-half
    rem = swz & 127;
    if (swz >> 7) { kOff = Klen; Cp = C1; }
  }
  const int m0 = (CM ? (rem % gx) : (rem / gx)) * 256;
  const int n0 = (CM ? (rem / gx) : (rem % gx)) * 256;

  const int sRow = w * 16 + (lane >> 2);
  const int sSwz = ((lane & 3) ^ ((lane >> 3) & 3)) * 8;
  const short* aG0 = A  + (size_t)(m0 + sRow) * Kpitch + kOff + sSwz;
  const short* aG1 = A  + (size_t)(m0 + 128 + sRow) * Kpitch + kOff + sSwz;
  const short* bG0 = BT + (size_t)(n0 + sRow) * Kpitch + kOff + sSwz;
  const short* bG1 = BT + (size_t)(n0 + 128 + sRow) * Kpitch + kOff + sSwz;

  f32x4 acc[8][4] = {};
  bf16x8 a0, a1, a2, a3, na0, na1, na2, na3;
  bf16x8 b0, b1, b2, b3, nb0, nb1, nb2, nb3;

  STAGE_A_(0, 0, 0) STAGE_A_(0, 1, 0) STAGE_B_(0, 0, 0) STAGE_B_(0, 1, 0)
  STAGE_A_(1, 0, 1) STAGE_B_(1, 0, 1)
  asm volatile("s_waitcnt vmcnt(4)" ::: "memory");
  __builtin_amdgcn_s_barrier();

  const int nIt = Klen >> 7;
  for (int i = 0; i < nIt; ++i) {
    const int c = 2 * i;
    const bool st = (i + 1 < nIt);
    // P1: load own (A00h0, B00) + prefetch P2 (A00h1)
    LD_A4(a0,a1,a2,a3, 0,0,0) LD_B4(b0,b1,b2,b3, 0,0) LD_A4(na0,na1,na2,na3, 0,0,1)
    STAGE_A_(1, 1, c + 1)
    BAR MM16(a0,a1,a2,a3, b0,b1,b2,b3, 0) BAR
    // P2: prefetch P3 (A01h0 + B01)
    LD_A4(a0,a1,a2,a3, 0,1,0) LD_B4(nb0,nb1,nb2,nb3, 0,1)
    STAGE_B_(1, 1, c + 1)
    BAR MM16(na0,na1,na2,na3, b0,b1,b2,b3, 1) BAR
    // P3: prefetch P4 (A01h1)
    LD_A4(na0,na1,na2,na3, 0,1,1)
    if (st) STAGE_A_(0, 0, c + 2)
    BAR MM16(a0,a1,a2,a3, nb0,nb1,nb2,nb3, 0) BAR
    // P4: no prefetch (P5's region needs this VM4+barrier)
    if (st) STAGE_B_(0, 0, c + 2)
    VM4
    BAR MM16(na0,na1,na2,na3, nb0,nb1,nb2,nb3, 1) BAR
    // P5: load own (A10h0, B10) + prefetch P6 (A10h1)
    LD_A4(a0,a1,a2,a3, 1,0,0) LD_B4(b0,b1,b2,b3, 1,0) LD_A4(na0,na1,na2,na3, 1,0,1)
    if (st) STAGE_A_(0, 1, c + 2)
    BAR MM16(a0,a1,a2,a3, b0,b1,b2,b3, 0) BAR
    // P6: prefetch P7 (A11h0 + B11)
    LD_A4(a0,a1,a2,a3, 1,1,0) LD_B4(nb0,nb1,nb2,nb3, 1,1)
    if (st) STAGE_B_(0, 1, c + 2)
    BAR MM16(na0,na1,na2,na3, b0,b1,b2,b3, 1) BAR
    // P7: prefetch P8 (A11h1)
    LD_A4(na0,na1,na2,na3, 1,1,1)
    if (st) STAGE_A_(1, 0, c + 3)
    BAR MM16(a0,a1,a2,a3, nb0,nb1,nb2,nb3, 0) BAR
    // P8: no prefetch (next P1's region needs this VM4+barrier)
    if (st) STAGE_B_(1, 0, c + 3)
    VM4
    BAR MM16(na0,na1,na2,na3, nb0,nb1,nb2,nb3, 1) BAR
  }

  // ---- epilogue: LDS transpose (4 chunks of 64 rows x 256 cols, pitch 260) ----
  float* Cl = (float*)SMEM;
  const int g = lane >> 4;
  #pragma unroll
  for (int ch = 0; ch < 4; ++ch) {
    if (wm == (ch >> 1)) {
      #pragma unroll
      for (int ii2 = 0; ii2 < 4; ++ii2)
        #pragma unroll
        for (int j = 0; j < 4; ++j)
          #pragma unroll
          for (int r = 0; r < 4; ++r)
            Cl[(ii2*16 + g*4 + r) * 260 + wn*64 + j*16 + l15] = acc[(ch & 1)*4 + ii2][j][r];
    }
    asm volatile("s_waitcnt lgkmcnt(0)" ::: "memory");
    __builtin_amdgcn_s_barrier();
    #pragma unroll
    for (int p = 0; p < 4; ++p) {
      const int row = (t >> 5) + p * 16;
      const int c8 = (t & 31) * 8;
      f32x4 v0 = *(const f32x4*)&Cl[row * 260 + c8];
      f32x4 v1 = *(const f32x4*)&Cl[row * 260 + c8 + 4];
      const int grow = m0 + ch * 64 + row;
      if (OUTF32) {
        *(f32x4*)&((float*)Cp)[(size_t)grow * N + n0 + c8]     = v0;
        *(f32x4*)&((float*)Cp)[(size_t)grow * N + n0 + c8 + 4] = v1;
      } else {
        unsigned d0, d1, d2, d3;
        asm("v_cvt_pk_bf16_f32 %0, %1, %2" : "=v"(d0) : "v"(v0[0]), "v"(v0[1]));
        asm("v_cvt_pk_bf16_f32 %0, %1, %2" : "=v"(d1) : "v"(v0[2]), "v"(v0[3]));
        asm("v_cvt_pk_bf16_f32 %0, %1, %2" : "=v"(d2) : "v"(v1[0]), "v"(v1[1]));
        asm("v_cvt_pk_bf16_f32 %0, %1, %2" : "=v"(d3) : "v"(v1[2]), "v"(v1[3]));
        uint4 u = {d0, d1, d2, d3};
        *(uint4*)&((short*)Cp)[(size_t)grow * N + n0 + c8] = u;
      }
    }
    asm volatile("s_waitcnt lgkmcnt(0)" ::: "memory");
    __builtin_amdgcn_s_barrier();
  }
}
#undef As
#undef Bs

// ---------------- per-token: RMSNorm(q,k), gates, partial RoPE, in place ----------------
__global__ __launch_bounds__(256) void k_post(short* __restrict__ Ycat,
    const float* __restrict__ cosb, const float* __restrict__ sinb,
    const float* __restrict__ qw, const float* __restrict__ kw)
{
  const int tok = blockIdx.x;                 // b*S + s
  const int lane = threadIdx.x & 63, w = threadIdx.x >> 6;
  const size_t rowb = (size_t)tok * LW;
  const int d0 = lane * 4;

  float gq[4], gv[4];
  {
    s16x4 a  = *(const s16x4*)&Ycat[rowb + 10240 + d0];
    s16x4 bq = *(const s16x4*)&Ycat[rowb + 10240 + 256 + d0];
    #pragma unroll
    for (int j = 0; j < 4; ++j){ gq[j] = sigm(bf2f(a[j])); gv[j] = sigm(bf2f(bq[j])); }
  }
  float c4[4] = {0,0,0,0}, s4[4] = {0,0,0,0};
  if (lane < 16) {
    float4 c = *(const float4*)&cosb[(size_t)tok * 64 + d0];
    float4 s = *(const float4*)&sinb[(size_t)tok * 64 + d0];
    c4[0]=c.x; c4[1]=c.y; c4[2]=c.z; c4[3]=c.w;
    s4[0]=s.x; s4[1]=s.y; s4[2]=s.z; s4[3]=s.w;
  }
  float4 qv4 = *(const float4*)&qw[d0];
  float4 kv4 = *(const float4*)&kw[d0];
  float qwa[4] = {qv4.x, qv4.y, qv4.z, qv4.w};
  float kwa[4] = {kv4.x, kv4.y, kv4.z, kv4.w};

  #pragma unroll
  for (int hi = 0; hi < 4; ++hi) {
    const int hh = w * 4 + hi;
    const size_t off = rowb + hh * 512 + d0;
    s16x4 v = *(const s16x4*)&Ycat[off];
    float x[4];
    #pragma unroll
    for (int j = 0; j < 4; ++j) x[j] = bf2f(v[j]);
    float ss = x[0]*x[0] + x[1]*x[1] + x[2]*x[2] + x[3]*x[3];
    #pragma unroll
    for (int o2 = 1; o2 < 64; o2 <<= 1) ss += __shfl_xor(ss, o2);
    float rr = rsqrtf(ss * (1.0f/256.0f) + 1e-6f);
    #pragma unroll
    for (int j = 0; j < 4; ++j) x[j] = x[j] * rr * (1.0f + qwa[j]) * gq[j];
    float p[4];
    #pragma unroll
    for (int j = 0; j < 4; ++j) p[j] = __shfl_xor(x[j], 8);
    if (lane < 8)       { for (int j = 0; j < 4; ++j) x[j] = x[j]*c4[j] - p[j]*s4[j]; }
    else if (lane < 16) { for (int j = 0; j < 4; ++j) x[j] = x[j]*c4[j] + p[j]*s4[j]; }
    s16x4 o;
    #pragma unroll
    for (int j = 0; j < 4; ++j) o[j] = f2bf(x[j]);
    *(s16x4*)&Ycat[off] = o;
  }
  {
    const size_t off = rowb + 8192 + w * 256 + d0;
    s16x4 v = *(const s16x4*)&Ycat[off];
    float x[4];
    #pragma unroll
    for (int j = 0; j < 4; ++j) x[j] = bf2f(v[j]);
    float ss = x[0]*x[0] + x[1]*x[1] + x[2]*x[2] + x[3]*x[3];
    #pragma unroll
    for (int o2 = 1; o2 < 64; o2 <<= 1) ss += __shfl_xor(ss, o2);
    float rr = rsqrtf(ss * (1.0f/256.0f) + 1e-6f);
    #pragma unroll
    for (int j = 0; j < 4; ++j) x[j] = x[j] * rr * (1.0f + kwa[j]) * gq[j];
    float p[4];
    #pragma unroll
    for (int j = 0; j < 4; ++j) p[j] = __shfl_xor(x[j], 8);
    if (lane < 8)       { for (int j = 0; j < 4; ++j) x[j] = x[j]*c4[j] - p[j]*s4[j]; }
    else if (lane < 16) { for (int j = 0; j < 4; ++j) x[j] = x[j]*c4[j] + p[j]*s4[j]; }
    s16x4 o;
    #pragma unroll
    for (int j = 0; j < 4; ++j) o[j] = f2bf(x[j]);
    *(s16x4*)&Ycat[off] = o;
  }
  {
    const size_t off = rowb + 9216 + w * 256 + d0;
    s16x4 v = *(const s16x4*)&Ycat[off];
    s16x4 o;
    #pragma unroll
    for (int j = 0; j < 4; ++j) o[j] = f2bf(bf2f(v[j]) * gv[j]);
    *(s16x4*)&Ycat[off] = o;
  }
}

// ====== flash attention v6: swapped QK, K-row permutation, in-register P,
//        static-max softmax (RMSNorm bounds |s|<=18.3) ======
#define JR(ri) (8 * (((ri)*2 + (tr >> 2)) & 3) + 4 * ((ri) >> 1) + (tr & 3))
#define ATT_STAGE(bb, jj) { \
  _Pragma("unroll") \
  for (int ri = 0; ri < 4; ++ri) \
    gload16(kSrc + (size_t)((jj) + JR(ri)) * LW, &Ks[bb][t*8 + ri*2048]); \
  _Pragma("unroll") \
  for (int ri = 0; ri < 4; ++ri) \
    gload16(vSrc + (jj) + (size_t)(ri*64) * S_LEN, &Vs[bb][t*8 + ri*2048]); }

__global__ __launch_bounds__(256) void k_attn(const short* __restrict__ Ycat,
                                              const short* __restrict__ VT,
                                              short* __restrict__ AO)
{
  __shared__ __align__(16) short Ks[2][8192];   // [buf][32 rows x 256] (rows permuted)
  __shared__ __align__(16) short Vs[2][8192];   // [buf][256 rows x 32]

  const int t = threadIdx.x, lane = t & 63, w = t >> 6;
  const int l15 = lane & 15, g = lane >> 4;
  const int id = blockIdx.x;
  const int xcd = id & 7, widx = id >> 3;
  const int b = xcd >> 2, hk = xcd & 3;
  const int h = hk * 4 + (widx & 3);
  const int x = widx >> 2, qq = x & 7, jj = x >> 3;
  const int qsel = (jj == 0) ? 31 - qq : (jj == 1) ? 16 + qq : (jj == 2) ? 15 - qq : qq;
  const int q0 = qsel * 64;
  const int qg = q0 + w * 16 + l15;        // this lane's q-row (global)
  const float SC2 = 0.09016844f;           // 1/16 * log2(e)
  const float MSH = 1.8033688f;            // 20 * SC2 (static max shift)

  bf16x8 qf[8];
  {
    const size_t qb = ((size_t)(b * S_LEN) + qg) * LW + h * 512 + g * 8;
    #pragma unroll
    for (int kk = 0; kk < 8; ++kk)
      qf[kk] = *(const bf16x8*)&Ycat[qb + kk * 32];
  }
  asm volatile("s_waitcnt vmcnt(0)" ::: "memory");

  const int tr = t >> 5;                   // LDS K row (mod 8), swizzle-invariant
  const int kColS = ((((t & 31) * 16) ^ (tr << 4)) >> 1);
  const int vRow = t >> 2;
  const int vColS = ((((t & 3) * 16) ^ ((vRow & 3) << 4)) >> 1);
  const short* kSrc = Ycat + (size_t)(b * S_LEN) * LW + 8192 + hk * 256 + kColS;
  const short* vSrc = VT + ((size_t)((b * NKV + hk) * HDIM + vRow)) * S_LEN + vColS;

  f32x4 oacc[16] = {};
  float l_r = 0.0f;                        // per-lane partial (8 keys/tile)

  const int nt = (q0 >> 5) + 2;
  ATT_STAGE(0, 0)
  int buf = 0;

  for (int ti = 0; ti < nt; ++ti) {
    const int j0 = ti * 32;
    const int jn = (ti + 1 < nt) ? j0 + 32 : 0;   // dummy re-stage keeps vmcnt uniform
    ATT_STAGE(buf ^ 1, jn)
    asm volatile("s_waitcnt vmcnt(8)" ::: "memory");
    __builtin_amdgcn_s_barrier();

    if (j0 <= q0 + w * 16 + 15) {                 // wave-uniform causal skip
      f32x4 sa[2] = {};
      #pragma unroll
      for (int kk = 0; kk < 8; ++kk) {
        #pragma unroll
        for (int c = 0; c < 2; ++c) {
          const int row = c * 16 + l15;
          bf16x8 kf = *(const bf16x8*)((const char*)Ks[buf] + row * 512
                       + ((kk * 64 + g * 16) ^ ((l15 & 7) << 4)));
          sa[c] = __builtin_amdgcn_mfma_f32_16x16x32_bf16(kf, qf[kk], sa[c], 0, 0, 0);
        }
      }
      float s[8];
      #pragma unroll
      for (int c = 0; c < 2; ++c)
        #pragma unroll
        for (int r = 0; r < 4; ++r) s[c * 4 + r] = sa[c][r];
      if (j0 + 31 > qg) {
        #pragma unroll
        for (int c = 0; c < 2; ++c)
          #pragma unroll
          for (int r = 0; r < 4; ++r)
            if (j0 + 8 * g + 4 * c + r > qg) s[c * 4 + r] = -1e30f;
      }
      float p[8];
      #pragma unroll
      for (int i = 0; i < 8; ++i) { p[i] = exp2f(fmaf(s[i], SC2, -MSH)); l_r += p[i]; }
      union { uint4 u; bf16x8 v; } pk;
      asm("v_cvt_pk_bf16_f32 %0, %1, %2" : "=v"(pk.u.x) : "v"(p[0]), "v"(p[1]));
      asm("v_cvt_pk_bf16_f32 %0, %1, %2" : "=v"(pk.u.y) : "v"(p[2]), "v"(p[3]));
      asm("v_cvt_pk_bf16_f32 %0, %1, %2" : "=v"(pk.u.z) : "v"(p[4]), "v"(p[5]));
      asm("v_cvt_pk_bf16_f32 %0, %1, %2" : "=v"(pk.u.w) : "v"(p[6]), "v"(p[7]));
      const bf16x8 pa = pk.v;
      #pragma unroll
      for (int jb = 0; jb < 16; ++jb) {
        const int vrow = jb * 16 + l15;
        bf16x8 vf = *(const bf16x8*)((const char*)Vs[buf] + vrow * 64
                     + ((16 * g) ^ ((l15 & 3) << 4)));
        oacc[jb] = __builtin_amdgcn_mfma_f32_16x16x32_bf16(vf, pa, oacc[jb], 0, 0, 0);
      }
    }
    __builtin_amdgcn_s_barrier();
    buf ^= 1;
  }
  asm volatile("s_waitcnt vmcnt(0)" ::: "memory");  // drain dummy stage

  float l = l_r;
  l += __shfl_xor(l, 16);
  l += __shfl_xor(l, 32);
  const float linv = 1.0f / l;
  const size_t gb = ((size_t)(b * S_LEN) + qg) * LW + h * 512 + 256;
  const size_t ob = ((size_t)(b * S_LEN) + qg) * 4096 + h * 256;
  #pragma unroll
  for (int jb = 0; jb < 16; ++jb) {
    const int d0 = jb * 16 + g * 4;
    s16x4 gt = *(const s16x4*)&Ycat[gb + d0];
    s16x4 o;
    #pragma unroll
    for (int r = 0; r < 4; ++r)
      o[r] = f2bf(oacc[jb][r] * linv * sigm(bf2f(gt[r])));
    *(s16x4*)&AO[ob + d0] = o;
  }
}

extern "C" void kernel_launch(void* const* d_in, const int* in_sizes, int n_in,
                              void* d_out, int out_size, void* d_ws, size_t ws_size,
                              hipStream_t stream) {
  const float* X    = (const float*)d_in[0];
  const float* cosb = (const float*)d_in[1];
  const float* sinb = (const float*)d_in[2];
  const float* Wq   = (const float*)d_in[4];
  const float* Wk   = (const float*)d_in[5];
  const float* Wv   = (const float*)d_in[6];
  const float* Wo   = (const float*)d_in[7];
  const float* qw   = (const float*)d_in[8];
  const float* kw   = (const float*)d_in[9];
  const float* Wr   = (const float*)d_in[10];

  short* Xb    = (short*)d_ws;                       //  8,388,608
  short* WcatT = Xb    +  8388608;                   // 22,020,096
  short* AO    = WcatT;                              // alias (dead after GEMM0)
  short* WoT   = WcatT + 22020096;                   //  8,388,608
  short* Ycat  = WoT   +  8388608;                   // 44,040,192
  short* VT    = Ycat  + 44040192;                   //  4,194,304
  float* P1    = (float*)Ycat;                       // split-K partial (Ycat dead then)

  dim3 tb(32, 8);
  // fused: weight transposes (7424 tiles) + X convert (8192 chunks) = 15616
  k_wt<<<15616, tb, 0, stream>>>(X, Wq, Wk, Wv, Wr, Wo, Xb, WcatT, WoT);

  k_gemm2<0, 1, 0><<<672, 512, 0, stream>>>(Xb, WcatT, Ycat, nullptr,
                                            4096, 10752, 2048, 2048, 16);
  k_post<<<4096, 256, 0, stream>>>(Ycat, cosb, sinb, qw, kw);
  k_vt<<<dim3(64, 8, 8), tb, 0, stream>>>(Ycat, VT);
  k_attn<<<1024, 256, 0, stream>>>(Ycat, VT, AO);
  k_gemm2<1, 0, 1><<<256, 512, 0, stream>>>(AO, WoT, d_out, P1,
                                            4096, 2048, 4096, 2048, 8);
  // d_out has 4096*2048 = 8,388,608 floats = 2,097,152 float4s
  k_add<<<2048, 256, 0, stream>>>(P1, (float*)d_out, 2097152);
}